// Round 2
// 2748.218 us; speedup vs baseline: 1.1077x; 1.1077x over previous
//
#include <hip/hip_runtime.h>
#include <math.h>

typedef unsigned short u16;
typedef unsigned int   u32;
typedef long long      i64;
typedef __attribute__((ext_vector_type(8))) __bf16 bf16x8;
typedef __attribute__((ext_vector_type(4))) float  f32x4;
typedef __attribute__((ext_vector_type(8))) u16    u16x8;
typedef __attribute__((ext_vector_type(4))) u16    u16x4;

#define LN_EPS 1e-12f

__device__ __forceinline__ float b2f(u16 u){ union {u32 i; float f;} v; v.i = ((u32)u)<<16; return v.f; }
__device__ __forceinline__ u16 f2b(float f){ union {float f; u32 i;} v; v.f = f; u32 r = v.i + 0x7FFFu + ((v.i>>16)&1u); return (u16)(r>>16); }

__device__ __forceinline__ void gl2lds16(const u16* g, u16* l) {
  __builtin_amdgcn_global_load_lds((const __attribute__((address_space(1))) void*)g,
                                   (__attribute__((address_space(3))) void*)l, 16, 0, 0);
}

// ---------------------------------------------------------------- GEMM (B^T)
// C[m][n] = sum_k A[m][k] * Bt[n][k] (+f32 bias, +gelu). A/Bt bf16; C bf16 or f32.
struct GemmArgs {
  const u16* A; const u16* Bt; void* C;
  const float* bias0; const float* bias1; const float* bias2;
  i64 sAb, sAh, sBb, sBh, sCb, sCh;
  int lda, ldb, ldc, M, N, K, bias_seg, act, hdiv, cf32;
};

template<int BM, int BN, int WM, int WN>
__global__ __launch_bounds__(WM*WN*64)
void gemm_bt(GemmArgs g) {
  constexpr int NT = WM*WN*64;
  constexpr int RA = (BM*32)/(NT*8);
  constexpr int RB = (BN*32)/(NT*8);
  __shared__ u16 As[BM*32];
  __shared__ u16 Bs[BN*32];
  const int tid  = threadIdx.x;
  const int wave = tid >> 6, lane = tid & 63;
  const int wm = wave / WN, wn = wave % WN;
  const int z  = blockIdx.z;
  const int zb = z / g.hdiv, zh = z % g.hdiv;
  const u16* A  = g.A  + (i64)zb*g.sAb + (i64)zh*g.sAh + (i64)blockIdx.x*BM*g.lda;
  const u16* Bt = g.Bt + (i64)zb*g.sBb + (i64)zh*g.sBh;
  const int n0 = blockIdx.y * BN;
  const int lrow = lane & 15, quad = lane >> 4;

  f32x4 acc[4][4];
  #pragma unroll
  for (int i=0;i<4;i++)
    #pragma unroll
    for (int j=0;j<4;j++) acc[i][j] = (f32x4){0.f,0.f,0.f,0.f};

  for (int k0 = 0; k0 < g.K; k0 += 32) {
    #pragma unroll
    for (int r = 0; r < RA; r++) {
      int gran = r*NT + tid;
      int row = gran >> 2;
      int col = (gran & 3) << 3;
      const u16* src = A + (i64)row*g.lda + k0 + col;
      int base = (r*NT + (wave<<6)) << 3;       // wave-uniform LDS base (elements)
      gl2lds16(src, &As[base]);
    }
    #pragma unroll
    for (int r = 0; r < RB; r++) {
      int gran = r*NT + tid;
      int row = gran >> 2;
      int nrow = n0 + row; if (nrow >= g.N) nrow = g.N - 1;   // clamp (stores guarded)
      int col = (gran & 3) << 3;
      const u16* src = Bt + (i64)nrow*g.ldb + k0 + col;
      int base = (r*NT + (wave<<6)) << 3;
      gl2lds16(src, &Bs[base]);
    }
    __syncthreads();
    bf16x8 af[4], bfv[4];
    #pragma unroll
    for (int i=0;i<4;i++) af[i]  = *(const bf16x8*)&As[(((wm<<6)+(i<<4)+lrow)<<5) + (quad<<3)];
    #pragma unroll
    for (int j=0;j<4;j++) bfv[j] = *(const bf16x8*)&Bs[(((wn<<6)+(j<<4)+lrow)<<5) + (quad<<3)];
    #pragma unroll
    for (int i=0;i<4;i++)
      #pragma unroll
      for (int j=0;j<4;j++)
        acc[i][j] = __builtin_amdgcn_mfma_f32_16x16x32_bf16(af[i], bfv[j], acc[i][j], 0,0,0);
    __syncthreads();
  }

  const i64 rowbase = (i64)blockIdx.x*BM + (wm<<6);
  u16*   Cb = (u16*)g.C   + (i64)zb*g.sCb + (i64)zh*g.sCh;
  float* Cf = (float*)g.C + (i64)zb*g.sCb + (i64)zh*g.sCh;
  #pragma unroll
  for (int i=0;i<4;i++) {
    #pragma unroll
    for (int j=0;j<4;j++) {
      int col = n0 + (wn<<6) + (j<<4) + lrow;
      if (col < g.N) {
        float bias = 0.f;
        if (g.bias0) {
          int seg = col / g.bias_seg;
          const float* bp = (seg==0) ? g.bias0 : ((seg==1) ? g.bias1 : g.bias2);
          bias = bp[col - seg*g.bias_seg];
        }
        #pragma unroll
        for (int r=0;r<4;r++) {
          i64 row = rowbase + (i<<4) + (quad<<2) + r;
          float v = acc[i][j][r] + bias;
          if (g.act == 1) v = 0.5f*v*(1.0f + erff(v*0.70710678118654752f));
          if (g.cf32) Cf[row*(i64)g.ldc + col] = v;
          else        Cb[row*(i64)g.ldc + col] = f2b(v);
        }
      }
    }
  }
}

// ---------------------------------------------------------------- fused flash attention
// One wave (64 thr) per (16 q-rows, b, h). Grid (32, 48). No LDS, no barriers.
// Q/K read from qkv (Q at col h*64, K at col 768+h*64, row stride 2304),
// V^T from VT[bh][64][512]. Output ctx[b*512+q][h*64+d] bf16.
//
// Swapped QK^T: S^T_tile = mfma(A=K_rows, B=Q_rows)  (contraction = d, 2x per 16 keys)
//   -> C[row=key_local=4g+r][col=q_local=lane&15], so each lane owns ONE q column:
//      row-softmax = 15 in-reg max/add + shfl_xor(16)+shfl_xor(32).
// PV: O^T = mfma(A=V^T rows, B=P^T)  (contraction = key, window of 32)
//   B-frag needs, per lane, keys kappa=8g+j (j=0..7) of the 32-key window, col=q=lane&15.
//   Held keys per lane (per 16-key subtile t): 4g+r. Element-wise mapping:
//     j=0..3 -> src lane group g'=2*(g&1), r=j ; j=4..7 -> g'=2*(g&1)+1, r=j-4 ;
//     subtile t = 2w + (g>>1).
__global__ __launch_bounds__(64) void flash_attn(const u16* __restrict__ qkv,
                                                 const u16* __restrict__ VT,
                                                 u16* __restrict__ ctx, int causal) {
  const int lane = threadIdx.x & 63;
  const int qi = lane & 15, g = lane >> 4;
  const int q0 = blockIdx.x << 4;            // 16 q-rows per wave
  const int bh = blockIdx.y;
  const int b = bh / 12, h = bh % 12;
  const int q = q0 + qi;

  // Q fragments (held for the whole kernel)
  const u16* Qp = qkv + (i64)(b*512 + q)*2304 + h*64 + (g<<3);
  bf16x8 qf0 = *(const bf16x8*)Qp;
  bf16x8 qf1 = *(const bf16x8*)(Qp + 32);

  const u16* Kp = qkv + ((i64)(b*512 + qi))*2304 + 768 + h*64 + (g<<3);
  const u16* Vp = VT + (i64)bh*32768 + (i64)qi*512 + (g<<3);

  f32x4 o[4];
  #pragma unroll
  for (int s=0;s<4;s++) o[s] = (f32x4){0.f,0.f,0.f,0.f};
  float m = -1e30f, lsum = 0.f;

  const int sA = qi + ((g & 1) << 5);   // source lane, lo-half (g' = 2*(g&1))
  const int sB = sA + 16;               // source lane, hi-half (g' = 2*(g&1)+1)
  const int tsel = g >> 1;              // which subtile round this lane consumes

  const int nt = causal ? (q0 >> 6) + 1 : 8;
  for (int kt = 0; kt < nt; ++kt) {
    const int kv0 = kt << 6;

    // K fragments: K[kv0+16t+qi][32w + 8g .. +7]
    bf16x8 kf[4][2];
    #pragma unroll
    for (int t=0;t<4;t++)
      #pragma unroll
      for (int w=0;w<2;w++)
        kf[t][w] = *(const bf16x8*)(Kp + (i64)(kv0 + (t<<4))*2304 + (w<<5));
    // V^T fragments: VT[16s+qi][kv0+32w + 8g .. +7]
    bf16x8 vf[4][2];
    #pragma unroll
    for (int s=0;s<4;s++)
      #pragma unroll
      for (int w=0;w<2;w++)
        vf[s][w] = *(const bf16x8*)(Vp + (s<<13) + kv0 + (w<<5));

    // QK^T (swapped): sc[t][r] = S[q][key=kv0+16t+4g+r]
    f32x4 sc[4];
    #pragma unroll
    for (int t=0;t<4;t++) {
      sc[t] = (f32x4){0.f,0.f,0.f,0.f};
      sc[t] = __builtin_amdgcn_mfma_f32_16x16x32_bf16(kf[t][0], qf0, sc[t], 0,0,0);
      sc[t] = __builtin_amdgcn_mfma_f32_16x16x32_bf16(kf[t][1], qf1, sc[t], 0,0,0);
    }

    // scale + causal mask
    float x[4][4];
    #pragma unroll
    for (int t=0;t<4;t++)
      #pragma unroll
      for (int r=0;r<4;r++) {
        float v = sc[t][r] * 0.125f;
        int key = kv0 + (t<<4) + (g<<2) + r;
        if (causal && key > q) v = -1e30f;
        x[t][r] = v;
      }

    // tile max over this q row (16 in-reg + across lane groups)
    float mt = x[0][0];
    #pragma unroll
    for (int t=0;t<4;t++)
      #pragma unroll
      for (int r=0;r<4;r++) mt = fmaxf(mt, x[t][r]);
    mt = fmaxf(mt, __shfl_xor(mt, 16));
    mt = fmaxf(mt, __shfl_xor(mt, 32));
    float mn = fmaxf(m, mt);
    float c = __expf(m - mn);
    m = mn;

    // P = exp(x - m), row sum
    float p[4][4];
    float ps = 0.f;
    #pragma unroll
    for (int t=0;t<4;t++)
      #pragma unroll
      for (int r=0;r<4;r++) { float e = __expf(x[t][r] - mn); p[t][r] = e; ps += e; }
    ps += __shfl_xor(ps, 16);
    ps += __shfl_xor(ps, 32);
    lsum = lsum * c + ps;
    #pragma unroll
    for (int s=0;s<4;s++) o[s] *= c;

    // pack P to bf16 pairs: pkLo[t]=(r0,r1), pkHi[t]=(r2,r3)
    u32 pkLo[4], pkHi[4];
    #pragma unroll
    for (int t=0;t<4;t++) {
      pkLo[t] = (u32)f2b(p[t][0]) | ((u32)f2b(p[t][1]) << 16);
      pkHi[t] = (u32)f2b(p[t][2]) | ((u32)f2b(p[t][3]) << 16);
    }

    // PV over the two 32-key windows
    #pragma unroll
    for (int w=0;w<2;w++) {
      u32 w0=0, w1=0, w2=0, w3=0;
      #pragma unroll
      for (int tl=0; tl<2; ++tl) {
        const int t = 2*w + tl;
        u32 aLo = (u32)__shfl((int)pkLo[t], sA);
        u32 aHi = (u32)__shfl((int)pkHi[t], sA);
        u32 bLo = (u32)__shfl((int)pkLo[t], sB);
        u32 bHi = (u32)__shfl((int)pkHi[t], sB);
        if (tsel == tl) { w0=aLo; w1=aHi; w2=bLo; w3=bHi; }
      }
      union { bf16x8 v; u32 u[4]; } pf;
      pf.u[0]=w0; pf.u[1]=w1; pf.u[2]=w2; pf.u[3]=w3;
      #pragma unroll
      for (int s=0;s<4;s++)
        o[s] = __builtin_amdgcn_mfma_f32_16x16x32_bf16(vf[s][w], pf.v, o[s], 0,0,0);
    }
  }

  // O[q][d] = o^T / lsum ; lane holds d = 16s + 4g + r, its own q
  float inv = 1.0f / lsum;
  u16* orow = ctx + (i64)(b*512 + q)*768 + h*64 + (g<<2);
  #pragma unroll
  for (int s=0;s<4;s++) {
    u16x4 ov;
    #pragma unroll
    for (int r=0;r<4;r++) ov[r] = f2b(o[s][r] * inv);
    *(u16x4*)(orow + (s<<4)) = ov;
  }
}

// ---------------------------------------------------------------- LN helpers
__device__ __forceinline__ float block_reduce_sum_256(float v, float* red) {
  #pragma unroll
  for (int off=32; off; off>>=1) v += __shfl_xor(v, off);
  int wave = threadIdx.x >> 6;
  __syncthreads();
  if ((threadIdx.x & 63) == 0) red[wave] = v;
  __syncthreads();
  return red[0]+red[1]+red[2]+red[3];
}

// y = LN(base + delta)*g + b  (all f32). Writes f32 master and bf16 mirror.
__global__ __launch_bounds__(256) void resln_kernel(const float* base, const float* delta,
                                                    const float* gam, const float* bet,
                                                    float* out_f, u16* out_b) {
  __shared__ float red[4];
  i64 off = (i64)blockIdx.x * 768;
  int tid = threadIdx.x;
  float x[3];
  #pragma unroll
  for (int j=0;j<3;j++) {
    int i = tid + j*256;
    float v = delta[off+i];
    if (base) v += base[off+i];
    x[j] = v;
  }
  float s = block_reduce_sum_256(x[0]+x[1]+x[2], red);
  float mean = s * (1.0f/768.0f);
  float q = 0.f;
  #pragma unroll
  for (int j=0;j<3;j++) { float d = x[j]-mean; q += d*d; }
  q = block_reduce_sum_256(q, red);
  float r = rsqrtf(q*(1.0f/768.0f) + LN_EPS);
  #pragma unroll
  for (int j=0;j<3;j++) {
    int i = tid + j*256;
    float y = (x[j]-mean)*r*gam[i] + bet[i];
    out_f[off+i] = y;
    out_b[off+i] = f2b(y);
  }
}

// h[row] = LN(word_emb[id] + pos_emb[s] + tok_emb[0])*g + b  (f32 in, f32+bf16 out)
__global__ __launch_bounds__(256) void embed_kernel(const int* ids, const float* wemb,
    const float* pemb, const float* temb, const float* gam, const float* bet,
    float* out_f, u16* out_b) {
  __shared__ float red[4];
  int row = blockIdx.x;
  int s = row & 511;
  i64 wrow = (i64)ids[row] * 768;
  i64 off = (i64)row * 768;
  int tid = threadIdx.x;
  float x[3];
  #pragma unroll
  for (int j=0;j<3;j++) {
    int i = tid + j*256;
    x[j] = wemb[wrow+i] + pemb[(i64)s*768+i] + temb[i];
  }
  float sm = block_reduce_sum_256(x[0]+x[1]+x[2], red);
  float mean = sm * (1.0f/768.0f);
  float q = 0.f;
  #pragma unroll
  for (int j=0;j<3;j++) { float d = x[j]-mean; q += d*d; }
  q = block_reduce_sum_256(q, red);
  float r = rsqrtf(q*(1.0f/768.0f) + LN_EPS);
  #pragma unroll
  for (int j=0;j<3;j++) {
    int i = tid + j*256;
    float y = (x[j]-mean)*r*gam[i] + bet[i];
    out_f[off+i] = y;
    out_b[off+i] = f2b(y);
  }
}

// f32 -> bf16 elementwise (encoder_hidden mirror)
__global__ __launch_bounds__(256) void cvt_kernel(const float* src, u16* dst, int n) {
  int i = (blockIdx.x*256 + threadIdx.x) * 4;
  if (i + 3 < n) {
    float4 v = *(const float4*)&src[i];
    dst[i+0]=f2b(v.x); dst[i+1]=f2b(v.y); dst[i+2]=f2b(v.z); dst[i+3]=f2b(v.w);
  }
}

// ---------------------------------------------------------------- transposes
struct TransEntry { const float* src; u16* dst; int K, N, tile0; };
struct TransArgs  { TransEntry e[12]; int n; };

// dst[n][k] = bf16(src[k][n]); 64x64 tiles; K % 64 == 0; N may be ragged.
__global__ __launch_bounds__(256) void transpose_multi(TransArgs ta) {
  __shared__ u16 tile[64][72];
  int t = blockIdx.x;
  int ei = 0;
  for (int i=1;i<ta.n;i++) if (t >= ta.e[i].tile0) ei = i;
  TransEntry E = ta.e[ei];
  int lt = t - E.tile0;
  int ntn = (E.N + 63) >> 6;
  int tk = lt / ntn, tn = lt - tk*ntn;
  int tid = threadIdx.x;
  int kk = tid >> 2, c = (tid & 3) << 4;
  i64 gk = (i64)(tk*64 + kk);
  int gn0 = tn*64 + c;
  const float* srow = E.src + gk * E.N;
  if (gn0 + 16 <= E.N) {
    #pragma unroll
    for (int j=0;j<16;j++) tile[kk][c+j] = f2b(srow[gn0+j]);
  } else {
    for (int j=0;j<16;j++) tile[kk][c+j] = (gn0+j < E.N) ? f2b(srow[gn0+j]) : (u16)0;
  }
  __syncthreads();
  int nn = tid >> 2, kc = (tid & 3) << 4;
  int gn = tn*64 + nn;
  if (gn < E.N) {
    u16x8 v0, v1;
    #pragma unroll
    for (int j=0;j<8;j++) { v0[j] = tile[kc+j][nn]; v1[j] = tile[kc+8+j][nn]; }
    u16* drow = E.dst + (i64)gn*E.K + tk*64 + kc;
    *(u16x8*)&drow[0] = v0;
    *(u16x8*)&drow[8] = v1;
  }
}

// VT[bh][d][key] = qkv[b*512+key][1536 + h*64 + d]   (bf16 -> bf16)
__global__ __launch_bounds__(256) void vtrans_kernel(const u16* qkv, u16* VT) {
  __shared__ u16 tile[64][72];
  int bh = blockIdx.z; int b = bh / 12, hh = bh % 12;
  const u16* src = qkv + (i64)b*512*2304 + 1536 + hh*64;
  u16* dst = VT + (i64)bh*64*512;
  int kt = blockIdx.x;
  int tid = threadIdx.x;
  int kk = tid >> 2, c = (tid & 3) << 4;
  const u32* p = (const u32*)&src[(i64)(kt*64+kk)*2304 + c];
  #pragma unroll
  for (int j=0;j<8;j++) *(u32*)&tile[kk][c + 2*j] = p[j];
  __syncthreads();
  int dd = tid >> 2, kc = (tid & 3) << 4;
  u16x8 v0, v1;
  #pragma unroll
  for (int j=0;j<8;j++) { v0[j] = tile[kc+j][dd]; v1[j] = tile[kc+8+j][dd]; }
  u16* drow = dst + (i64)dd*512 + kt*64 + kc;
  *(u16x8*)&drow[0] = v0;
  *(u16x8*)&drow[8] = v1;
}

// ---------------------------------------------------------------- host side
static void gemm128(const u16* A, int lda, const u16* Bt, int ldb, void* C, int ldc,
                    int M, int N, int K, const float* b0, const float* b1, const float* b2,
                    int bias_seg, int act, int cf32, hipStream_t st) {
  GemmArgs g;
  g.A=A; g.Bt=Bt; g.C=C; g.bias0=b0; g.bias1=b1; g.bias2=b2;
  g.sAb=0; g.sAh=0; g.sBb=0; g.sBh=0; g.sCb=0; g.sCh=0;
  g.lda=lda; g.ldb=ldb; g.ldc=ldc; g.M=M; g.N=N; g.K=K;
  g.bias_seg=bias_seg; g.act=act; g.hdiv=1; g.cf32=cf32;
  dim3 grid(M/128, (N+127)/128, 1);
  gemm_bt<128,128,2,2><<<grid, 256, 0, st>>>(g);
}

extern "C" void kernel_launch(void* const* d_in, const int* in_sizes, int n_in,
                              void* d_out, int out_size, void* d_ws, size_t ws_size,
                              hipStream_t stream) {
  (void)in_sizes; (void)n_in; (void)out_size;
  const int*   ids  = (const int*)d_in[0];
  const float* enc  = (const float*)d_in[1];
  const float* wemb = (const float*)d_in[2];
  const float* pemb = (const float*)d_in[3];
  const float* temb = (const float*)d_in[4];
  const float* eg   = (const float*)d_in[5];
  const float* eb   = (const float*)d_in[6];
  const float* Wq=(const float*)d_in[7];  const float* bq=(const float*)d_in[8];
  const float* Wk=(const float*)d_in[9];  const float* bk=(const float*)d_in[10];
  const float* Wv=(const float*)d_in[11]; const float* bv=(const float*)d_in[12];
  const float* Wo=(const float*)d_in[13]; const float* bo=(const float*)d_in[14];
  const float* l1g=(const float*)d_in[15]; const float* l1b=(const float*)d_in[16];
  const float* cWq=(const float*)d_in[17]; const float* cbq=(const float*)d_in[18];
  const float* cWk=(const float*)d_in[19]; const float* cbk=(const float*)d_in[20];
  const float* cWv=(const float*)d_in[21]; const float* cbv=(const float*)d_in[22];
  const float* cWo=(const float*)d_in[23]; const float* cbo=(const float*)d_in[24];
  const float* l2g=(const float*)d_in[25]; const float* l2b=(const float*)d_in[26];
  const float* Wi=(const float*)d_in[27];  const float* bi=(const float*)d_in[28];
  const float* Wf=(const float*)d_in[29];  const float* bff=(const float*)d_in[30];
  const float* l3g=(const float*)d_in[31]; const float* l3b=(const float*)d_in[32];
  const float* Wt=(const float*)d_in[33];  const float* bt=(const float*)d_in[34];
  const float* lhg=(const float*)d_in[35]; const float* lhb=(const float*)d_in[36];
  const float* Wdec=(const float*)d_in[37]; const float* bdec=(const float*)d_in[38];
  float* out = (float*)d_out;

  // workspace layout (u16 units)
  u16* ws     = (u16*)d_ws;
  u16* WT     = ws;                          // 24,030,720 u16 (reused per layer / head)
  u16* h_bf   = WT + 24030720;               // 1,572,864 u16
  float* h_f  = (float*)(h_bf + 1572864);    // 1,572,864 f32
  float* h2_f = h_f + 1572864;               // 1,572,864 f32
  u16* qkv    = (u16*)(h2_f + 1572864);      // 4,718,592 u16
  u16* ctx    = qkv + 4718592;               // 1,572,864 u16
  u16* VT     = ctx + 1572864;               // 1,572,864 u16
  u16* enc_bf = VT + 1572864;                // 1,572,864 u16
  u16* Smat   = enc_bf + 1572864;            // 12,582,912 u16 (now only FFN-mid alias)
  u16* mid    = Smat;                        // 6,291,456 u16 (FFN only)
  // total = 53,915,136 u16 = 107.8 MB
  if (ws_size < (size_t)53915136 * 2) return;

  const int DD = 589824, DF = 2359296;
  // per-layer WT sub-regions (bf16)
  u16* qkvT = WT;                 // 2304x768
  u16* woT  = WT + 1769472;       // 768x768
  u16* cqT  = WT + 2359296;       // 768x768
  u16* ckvT = WT + 2949120;       // 1536x768
  u16* cwoT = WT + 4128768;       // 768x768
  u16* wiT  = WT + 4718592;       // 3072x768
  u16* wfT  = WT + 7077888;       // 768x3072

  embed_kernel<<<2048, 256, 0, stream>>>(ids, wemb, pemb, temb, eg, eb, h_f, h_bf);
  cvt_kernel<<<1536, 256, 0, stream>>>(enc, enc_bf, 1572864);

  for (int l = 0; l < 6; l++) {
    // transpose+convert this layer's weights
    TransArgs ta; int tile = 0; int idx = 0;
    auto add = [&](const float* s, u16* d, int K, int N) {
      ta.e[idx].src=s; ta.e[idx].dst=d; ta.e[idx].K=K; ta.e[idx].N=N; ta.e[idx].tile0=tile;
      tile += (K/64)*((N+63)/64); idx++;
    };
    add(Wq +(i64)l*DD, qkvT,        768, 768);
    add(Wk +(i64)l*DD, qkvT+DD,     768, 768);
    add(Wv +(i64)l*DD, qkvT+2*DD,   768, 768);
    add(Wo +(i64)l*DD, woT,         768, 768);
    add(cWq+(i64)l*DD, cqT,         768, 768);
    add(cWk+(i64)l*DD, ckvT,        768, 768);
    add(cWv+(i64)l*DD, ckvT+DD,     768, 768);
    add(cWo+(i64)l*DD, cwoT,        768, 768);
    add(Wi +(i64)l*DF, wiT,         768, 3072);
    add(Wf +(i64)l*DF, wfT,         3072, 768);
    ta.n = idx;
    transpose_multi<<<tile, 256, 0, stream>>>(ta);

    // ---- self attention ----
    gemm128(h_bf, 768, qkvT, 768, qkv, 2304, 2048, 2304, 768,
            bq+l*768, bk+l*768, bv+l*768, 768, 0, 0, stream);
    vtrans_kernel<<<dim3(8,1,48), 256, 0, stream>>>(qkv, VT);
    flash_attn<<<dim3(32,48), 64, 0, stream>>>(qkv, VT, ctx, 1);
    gemm128(ctx, 768, woT, 768, h2_f, 768, 2048, 768, 768,
            bo+l*768, nullptr, nullptr, 768, 0, 1, stream);
    resln_kernel<<<2048, 256, 0, stream>>>(h_f, h2_f, l1g+l*768, l1b+l*768, h_f, h_bf);

    // ---- cross attention ----
    gemm128(h_bf, 768, cqT, 768, qkv, 2304, 2048, 768, 768,
            cbq+l*768, nullptr, nullptr, 768, 0, 0, stream);
    gemm128(enc_bf, 768, ckvT, 768, qkv+768, 2304, 2048, 1536, 768,
            cbk+l*768, cbv+l*768, nullptr, 768, 0, 0, stream);
    vtrans_kernel<<<dim3(8,1,48), 256, 0, stream>>>(qkv, VT);
    flash_attn<<<dim3(32,48), 64, 0, stream>>>(qkv, VT, ctx, 0);
    gemm128(ctx, 768, cwoT, 768, h2_f, 768, 2048, 768, 768,
            cbo+l*768, nullptr, nullptr, 768, 0, 1, stream);
    resln_kernel<<<2048, 256, 0, stream>>>(h_f, h2_f, l2g+l*768, l2b+l*768, h_f, h_bf);

    // ---- FFN ----
    gemm128(h_bf, 768, wiT, 768, mid, 3072, 2048, 3072, 768,
            bi+l*3072, nullptr, nullptr, 3072, 1, 0, stream);
    gemm128(mid, 3072, wfT, 3072, h2_f, 768, 2048, 768, 3072,
            bff+l*768, nullptr, nullptr, 768, 0, 1, stream);
    resln_kernel<<<2048, 256, 0, stream>>>(h_f, h2_f, l3g+l*768, l3b+l*768, h_f, h_bf);
  }

  // ---- MLM head ----
  u16* wtT   = WT;            // 768x768
  u16* wdecT = WT + 589824;   // 30522x768
  {
    TransArgs ta; int tile = 0; int idx = 0;
    auto add = [&](const float* s, u16* d, int K, int N) {
      ta.e[idx].src=s; ta.e[idx].dst=d; ta.e[idx].K=K; ta.e[idx].N=N; ta.e[idx].tile0=tile;
      tile += (K/64)*((N+63)/64); idx++;
    };
    add(Wt,   wtT,   768, 768);
    add(Wdec, wdecT, 768, 30522);
    ta.n = idx;
    transpose_multi<<<tile, 256, 0, stream>>>(ta);
  }
  gemm128(h_bf, 768, wtT, 768, h2_f, 768, 2048, 768, 768, bt, nullptr, nullptr, 768, 1, 1, stream);
  resln_kernel<<<2048, 256, 0, stream>>>(nullptr, h2_f, lhg, lhb, h_f, h_bf);
  gemm128(h_bf, 768, wdecT, 768, out, 30522, 2048, 30522, 768,
          bdec, nullptr, nullptr, 30522, 0, 1, stream);
}

// Round 3
// 2672.498 us; speedup vs baseline: 1.1391x; 1.0283x over previous
//
#include <hip/hip_runtime.h>
#include <math.h>

typedef unsigned short u16;
typedef unsigned int   u32;
typedef long long      i64;
typedef __attribute__((ext_vector_type(8))) __bf16 bf16x8;
typedef __attribute__((ext_vector_type(4))) float  f32x4;
typedef __attribute__((ext_vector_type(8))) u16    u16x8;
typedef __attribute__((ext_vector_type(4))) u16    u16x4;

#define LN_EPS 1e-12f

__device__ __forceinline__ float b2f(u16 u){ union {u32 i; float f;} v; v.i = ((u32)u)<<16; return v.f; }
__device__ __forceinline__ u16 f2b(float f){ union {float f; u32 i;} v; v.f = f; u32 r = v.i + 0x7FFFu + ((v.i>>16)&1u); return (u16)(r>>16); }

__device__ __forceinline__ void gl2lds16(const u16* g, u16* l) {
  __builtin_amdgcn_global_load_lds((const __attribute__((address_space(1))) void*)g,
                                   (__attribute__((address_space(3))) void*)l, 16, 0, 0);
}

// ---------------------------------------------------------------- GEMM (B^T)
// C[m][n] = sum_k A[m][k] * Bt[n][k] (+f32 bias, +gelu). A/Bt bf16; C bf16 or f32.
struct GemmArgs {
  const u16* A; const u16* Bt; void* C;
  const float* bias0; const float* bias1; const float* bias2;
  i64 sAb, sAh, sBb, sBh, sCb, sCh;
  int lda, ldb, ldc, M, N, K, bias_seg, act, hdiv, cf32;
};

template<int BM, int BN, int WM, int WN>
__global__ __launch_bounds__(WM*WN*64)
void gemm_bt(GemmArgs g) {
  constexpr int NT = WM*WN*64;
  constexpr int RA = (BM*32)/(NT*8);
  constexpr int RB = (BN*32)/(NT*8);
  __shared__ u16 As[BM*32];
  __shared__ u16 Bs[BN*32];
  const int tid  = threadIdx.x;
  const int wave = tid >> 6, lane = tid & 63;
  const int wm = wave / WN, wn = wave % WN;
  const int z  = blockIdx.z;
  const int zb = z / g.hdiv, zh = z % g.hdiv;

  // XCD-chunked bijective swizzle (m204): consecutive x-blocks (which share a
  // B-panel) land on the same XCD's L2.
  int bx, by;
  {
    const int gx = gridDim.x;
    const int nwg = gx * gridDim.y;
    const int wg = blockIdx.y * gx + blockIdx.x;
    const int q = nwg >> 3, r = nwg & 7;
    const int xcd = wg & 7, loc = wg >> 3;
    const int nid = (xcd < r ? xcd * (q + 1) : r * (q + 1) + (xcd - r) * q) + loc;
    bx = nid % gx; by = nid / gx;
  }

  const u16* A  = g.A  + (i64)zb*g.sAb + (i64)zh*g.sAh + (i64)bx*BM*g.lda;
  const u16* Bt = g.Bt + (i64)zb*g.sBb + (i64)zh*g.sBh;
  const int n0 = by * BN;
  const int lrow = lane & 15, quad = lane >> 4;

  f32x4 acc[4][4];
  #pragma unroll
  for (int i=0;i<4;i++)
    #pragma unroll
    for (int j=0;j<4;j++) acc[i][j] = (f32x4){0.f,0.f,0.f,0.f};

  for (int k0 = 0; k0 < g.K; k0 += 32) {
    #pragma unroll
    for (int r = 0; r < RA; r++) {
      int gran = r*NT + tid;
      int row = gran >> 2;
      int col = (gran & 3) << 3;
      const u16* src = A + (i64)row*g.lda + k0 + col;
      int base = (r*NT + (wave<<6)) << 3;       // wave-uniform LDS base (elements)
      gl2lds16(src, &As[base]);
    }
    #pragma unroll
    for (int r = 0; r < RB; r++) {
      int gran = r*NT + tid;
      int row = gran >> 2;
      int nrow = n0 + row; if (nrow >= g.N) nrow = g.N - 1;   // clamp (stores guarded)
      int col = (gran & 3) << 3;
      const u16* src = Bt + (i64)nrow*g.ldb + k0 + col;
      int base = (r*NT + (wave<<6)) << 3;
      gl2lds16(src, &Bs[base]);
    }
    __syncthreads();
    bf16x8 af[4], bfv[4];
    #pragma unroll
    for (int i=0;i<4;i++) af[i]  = *(const bf16x8*)&As[(((wm<<6)+(i<<4)+lrow)<<5) + (quad<<3)];
    #pragma unroll
    for (int j=0;j<4;j++) bfv[j] = *(const bf16x8*)&Bs[(((wn<<6)+(j<<4)+lrow)<<5) + (quad<<3)];
    #pragma unroll
    for (int i=0;i<4;i++)
      #pragma unroll
      for (int j=0;j<4;j++)
        acc[i][j] = __builtin_amdgcn_mfma_f32_16x16x32_bf16(af[i], bfv[j], acc[i][j], 0,0,0);
    __syncthreads();
  }

  const i64 rowbase = (i64)bx*BM + (wm<<6);
  u16*   Cb = (u16*)g.C   + (i64)zb*g.sCb + (i64)zh*g.sCh;
  float* Cf = (float*)g.C + (i64)zb*g.sCb + (i64)zh*g.sCh;
  #pragma unroll
  for (int i=0;i<4;i++) {
    #pragma unroll
    for (int j=0;j<4;j++) {
      int col = n0 + (wn<<6) + (j<<4) + lrow;
      if (col < g.N) {
        float bias = 0.f;
        if (g.bias0) {
          int seg = col / g.bias_seg;
          const float* bp = (seg==0) ? g.bias0 : ((seg==1) ? g.bias1 : g.bias2);
          bias = bp[col - seg*g.bias_seg];
        }
        #pragma unroll
        for (int r=0;r<4;r++) {
          i64 row = rowbase + (i<<4) + (quad<<2) + r;
          float v = acc[i][j][r] + bias;
          if (g.act == 1) v = 0.5f*v*(1.0f + erff(v*0.70710678118654752f));
          if (g.cf32) Cf[row*(i64)g.ldc + col] = v;
          else        Cb[row*(i64)g.ldc + col] = f2b(v);
        }
      }
    }
  }
}

// ---------------------------------------------------------------- fused flash attention
// One wave (64 thr) per (16 q-rows, b, h). Grid (32, 48). No LDS, no barriers.
__global__ __launch_bounds__(64) void flash_attn(const u16* __restrict__ qkv,
                                                 const u16* __restrict__ VT,
                                                 u16* __restrict__ ctx, int causal) {
  const int lane = threadIdx.x & 63;
  const int qi = lane & 15, g = lane >> 4;
  const int q0 = blockIdx.x << 4;            // 16 q-rows per wave
  const int bh = blockIdx.y;
  const int b = bh / 12, h = bh % 12;
  const int q = q0 + qi;

  // Q fragments (held for the whole kernel)
  const u16* Qp = qkv + (i64)(b*512 + q)*2304 + h*64 + (g<<3);
  bf16x8 qf0 = *(const bf16x8*)Qp;
  bf16x8 qf1 = *(const bf16x8*)(Qp + 32);

  const u16* Kp = qkv + ((i64)(b*512 + qi))*2304 + 768 + h*64 + (g<<3);
  const u16* Vp = VT + (i64)bh*32768 + (i64)qi*512 + (g<<3);

  f32x4 o[4];
  #pragma unroll
  for (int s=0;s<4;s++) o[s] = (f32x4){0.f,0.f,0.f,0.f};
  float m = -1e30f, lsum = 0.f;

  const int sA = qi + ((g & 1) << 5);   // source lane, lo-half
  const int sB = sA + 16;               // source lane, hi-half
  const int tsel = g >> 1;              // which subtile round this lane consumes

  const int nt = causal ? (q0 >> 6) + 1 : 8;
  for (int kt = 0; kt < nt; ++kt) {
    const int kv0 = kt << 6;

    // K fragments: K[kv0+16t+qi][32w + 8g .. +7]
    bf16x8 kf[4][2];
    #pragma unroll
    for (int t=0;t<4;t++)
      #pragma unroll
      for (int w=0;w<2;w++)
        kf[t][w] = *(const bf16x8*)(Kp + (i64)(kv0 + (t<<4))*2304 + (w<<5));
    // V^T fragments: VT[16s+qi][kv0+32w + 8g .. +7]
    bf16x8 vf[4][2];
    #pragma unroll
    for (int s=0;s<4;s++)
      #pragma unroll
      for (int w=0;w<2;w++)
        vf[s][w] = *(const bf16x8*)(Vp + (s<<13) + kv0 + (w<<5));

    // QK^T (swapped): sc[t][r] = S[q][key=kv0+16t+4g+r]
    f32x4 sc[4];
    #pragma unroll
    for (int t=0;t<4;t++) {
      sc[t] = (f32x4){0.f,0.f,0.f,0.f};
      sc[t] = __builtin_amdgcn_mfma_f32_16x16x32_bf16(kf[t][0], qf0, sc[t], 0,0,0);
      sc[t] = __builtin_amdgcn_mfma_f32_16x16x32_bf16(kf[t][1], qf1, sc[t], 0,0,0);
    }

    // scale + causal mask
    float x[4][4];
    #pragma unroll
    for (int t=0;t<4;t++)
      #pragma unroll
      for (int r=0;r<4;r++) {
        float v = sc[t][r] * 0.125f;
        int key = kv0 + (t<<4) + (g<<2) + r;
        if (causal && key > q) v = -1e30f;
        x[t][r] = v;
      }

    // tile max over this q row
    float mt = x[0][0];
    #pragma unroll
    for (int t=0;t<4;t++)
      #pragma unroll
      for (int r=0;r<4;r++) mt = fmaxf(mt, x[t][r]);
    mt = fmaxf(mt, __shfl_xor(mt, 16));
    mt = fmaxf(mt, __shfl_xor(mt, 32));
    float mn = fmaxf(m, mt);
    float c = __expf(m - mn);
    m = mn;

    // P = exp(x - m), row sum
    float p[4][4];
    float ps = 0.f;
    #pragma unroll
    for (int t=0;t<4;t++)
      #pragma unroll
      for (int r=0;r<4;r++) { float e = __expf(x[t][r] - mn); p[t][r] = e; ps += e; }
    ps += __shfl_xor(ps, 16);
    ps += __shfl_xor(ps, 32);
    lsum = lsum * c + ps;
    #pragma unroll
    for (int s=0;s<4;s++) o[s] *= c;

    // pack P to bf16 pairs: pkLo[t]=(r0,r1), pkHi[t]=(r2,r3)
    u32 pkLo[4], pkHi[4];
    #pragma unroll
    for (int t=0;t<4;t++) {
      pkLo[t] = (u32)f2b(p[t][0]) | ((u32)f2b(p[t][1]) << 16);
      pkHi[t] = (u32)f2b(p[t][2]) | ((u32)f2b(p[t][3]) << 16);
    }

    // PV over the two 32-key windows
    #pragma unroll
    for (int w=0;w<2;w++) {
      u32 w0=0, w1=0, w2=0, w3=0;
      #pragma unroll
      for (int tl=0; tl<2; ++tl) {
        const int t = 2*w + tl;
        u32 aLo = (u32)__shfl((int)pkLo[t], sA);
        u32 aHi = (u32)__shfl((int)pkHi[t], sA);
        u32 bLo = (u32)__shfl((int)pkLo[t], sB);
        u32 bHi = (u32)__shfl((int)pkHi[t], sB);
        if (tsel == tl) { w0=aLo; w1=aHi; w2=bLo; w3=bHi; }
      }
      union { bf16x8 v; u32 u[4]; } pf;
      pf.u[0]=w0; pf.u[1]=w1; pf.u[2]=w2; pf.u[3]=w3;
      #pragma unroll
      for (int s=0;s<4;s++)
        o[s] = __builtin_amdgcn_mfma_f32_16x16x32_bf16(vf[s][w], pf.v, o[s], 0,0,0);
    }
  }

  // O[q][d] = o^T / lsum ; lane holds d = 16s + 4g + r, its own q
  float inv = 1.0f / lsum;
  u16* orow = ctx + (i64)(b*512 + q)*768 + h*64 + (g<<2);
  #pragma unroll
  for (int s=0;s<4;s++) {
    u16x4 ov;
    #pragma unroll
    for (int r=0;r<4;r++) ov[r] = f2b(o[s][r] * inv);
    *(u16x4*)(orow + (s<<4)) = ov;
  }
}

// ---------------------------------------------------------------- LN helpers
__device__ __forceinline__ float block_reduce_sum_256(float v, float* red) {
  #pragma unroll
  for (int off=32; off; off>>=1) v += __shfl_xor(v, off);
  int wave = threadIdx.x >> 6;
  __syncthreads();
  if ((threadIdx.x & 63) == 0) red[wave] = v;
  __syncthreads();
  return red[0]+red[1]+red[2]+red[3];
}

// y = LN(base + delta)*g + b  (all f32). Writes f32 master and bf16 mirror.
__global__ __launch_bounds__(256) void resln_kernel(const float* base, const float* delta,
                                                    const float* gam, const float* bet,
                                                    float* out_f, u16* out_b) {
  __shared__ float red[4];
  i64 off = (i64)blockIdx.x * 768;
  int tid = threadIdx.x;
  float x[3];
  #pragma unroll
  for (int j=0;j<3;j++) {
    int i = tid + j*256;
    float v = delta[off+i];
    if (base) v += base[off+i];
    x[j] = v;
  }
  float s = block_reduce_sum_256(x[0]+x[1]+x[2], red);
  float mean = s * (1.0f/768.0f);
  float q = 0.f;
  #pragma unroll
  for (int j=0;j<3;j++) { float d = x[j]-mean; q += d*d; }
  q = block_reduce_sum_256(q, red);
  float r = rsqrtf(q*(1.0f/768.0f) + LN_EPS);
  #pragma unroll
  for (int j=0;j<3;j++) {
    int i = tid + j*256;
    float y = (x[j]-mean)*r*gam[i] + bet[i];
    out_f[off+i] = y;
    out_b[off+i] = f2b(y);
  }
}

// h[row] = LN(word_emb[id] + pos_emb[s] + tok_emb[0])*g + b  (f32 in, f32+bf16 out)
__global__ __launch_bounds__(256) void embed_kernel(const int* ids, const float* wemb,
    const float* pemb, const float* temb, const float* gam, const float* bet,
    float* out_f, u16* out_b) {
  __shared__ float red[4];
  int row = blockIdx.x;
  int s = row & 511;
  i64 wrow = (i64)ids[row] * 768;
  i64 off = (i64)row * 768;
  int tid = threadIdx.x;
  float x[3];
  #pragma unroll
  for (int j=0;j<3;j++) {
    int i = tid + j*256;
    x[j] = wemb[wrow+i] + pemb[(i64)s*768+i] + temb[i];
  }
  float sm = block_reduce_sum_256(x[0]+x[1]+x[2], red);
  float mean = sm * (1.0f/768.0f);
  float q = 0.f;
  #pragma unroll
  for (int j=0;j<3;j++) { float d = x[j]-mean; q += d*d; }
  q = block_reduce_sum_256(q, red);
  float r = rsqrtf(q*(1.0f/768.0f) + LN_EPS);
  #pragma unroll
  for (int j=0;j<3;j++) {
    int i = tid + j*256;
    float y = (x[j]-mean)*r*gam[i] + bet[i];
    out_f[off+i] = y;
    out_b[off+i] = f2b(y);
  }
}

// f32 -> bf16 elementwise (encoder_hidden mirror)
__global__ __launch_bounds__(256) void cvt_kernel(const float* src, u16* dst, int n) {
  int i = (blockIdx.x*256 + threadIdx.x) * 4;
  if (i + 3 < n) {
    float4 v = *(const float4*)&src[i];
    dst[i+0]=f2b(v.x); dst[i+1]=f2b(v.y); dst[i+2]=f2b(v.z); dst[i+3]=f2b(v.w);
  }
}

// ---------------------------------------------------------------- transposes
struct TransEntry { const float* src; u16* dst; int K, N, tile0; };
struct TransArgs  { TransEntry e[12]; int n; };

// dst[n][k] = bf16(src[k][n]); 64x64 tiles; K % 64 == 0; N may be ragged.
__global__ __launch_bounds__(256) void transpose_multi(TransArgs ta) {
  __shared__ u16 tile[64][72];
  int t = blockIdx.x;
  int ei = 0;
  for (int i=1;i<ta.n;i++) if (t >= ta.e[i].tile0) ei = i;
  TransEntry E = ta.e[ei];
  int lt = t - E.tile0;
  int ntn = (E.N + 63) >> 6;
  int tk = lt / ntn, tn = lt - tk*ntn;
  int tid = threadIdx.x;
  int kk = tid >> 2, c = (tid & 3) << 4;
  i64 gk = (i64)(tk*64 + kk);
  int gn0 = tn*64 + c;
  const float* srow = E.src + gk * E.N;
  if (gn0 + 16 <= E.N) {
    #pragma unroll
    for (int j=0;j<16;j++) tile[kk][c+j] = f2b(srow[gn0+j]);
  } else {
    for (int j=0;j<16;j++) tile[kk][c+j] = (gn0+j < E.N) ? f2b(srow[gn0+j]) : (u16)0;
  }
  __syncthreads();
  int nn = tid >> 2, kc = (tid & 3) << 4;
  int gn = tn*64 + nn;
  if (gn < E.N) {
    u16x8 v0, v1;
    #pragma unroll
    for (int j=0;j<8;j++) { v0[j] = tile[kc+j][nn]; v1[j] = tile[kc+8+j][nn]; }
    u16* drow = E.dst + (i64)gn*E.K + tk*64 + kc;
    *(u16x8*)&drow[0] = v0;
    *(u16x8*)&drow[8] = v1;
  }
}

// VT[bh][d][key] = qkv[b*512+key][1536 + h*64 + d]   (bf16 -> bf16)
__global__ __launch_bounds__(256) void vtrans_kernel(const u16* qkv, u16* VT) {
  __shared__ u16 tile[64][72];
  int bh = blockIdx.z; int b = bh / 12, hh = bh % 12;
  const u16* src = qkv + (i64)b*512*2304 + 1536 + hh*64;
  u16* dst = VT + (i64)bh*64*512;
  int kt = blockIdx.x;
  int tid = threadIdx.x;
  int kk = tid >> 2, c = (tid & 3) << 4;
  const u32* p = (const u32*)&src[(i64)(kt*64+kk)*2304 + c];
  #pragma unroll
  for (int j=0;j<8;j++) *(u32*)&tile[kk][c + 2*j] = p[j];
  __syncthreads();
  int dd = tid >> 2, kc = (tid & 3) << 4;
  u16x8 v0, v1;
  #pragma unroll
  for (int j=0;j<8;j++) { v0[j] = tile[kc+j][dd]; v1[j] = tile[kc+8+j][dd]; }
  u16* drow = dst + (i64)dd*512 + kt*64 + kc;
  *(u16x8*)&drow[0] = v0;
  *(u16x8*)&drow[8] = v1;
}

// ---------------------------------------------------------------- host side
static void gemm_args(GemmArgs& g, const u16* A, int lda, const u16* Bt, int ldb,
                      void* C, int ldc, int M, int N, int K, const float* b0,
                      const float* b1, const float* b2, int bias_seg, int act, int cf32) {
  g.A=A; g.Bt=Bt; g.C=C; g.bias0=b0; g.bias1=b1; g.bias2=b2;
  g.sAb=0; g.sAh=0; g.sBb=0; g.sBh=0; g.sCb=0; g.sCh=0;
  g.lda=lda; g.ldb=ldb; g.ldc=ldc; g.M=M; g.N=N; g.K=K;
  g.bias_seg=bias_seg; g.act=act; g.hdiv=1; g.cf32=cf32;
}

static void gemm128(const u16* A, int lda, const u16* Bt, int ldb, void* C, int ldc,
                    int M, int N, int K, const float* b0, const float* b1, const float* b2,
                    int bias_seg, int act, int cf32, hipStream_t st) {
  GemmArgs g; gemm_args(g, A, lda, Bt, ldb, C, ldc, M, N, K, b0, b1, b2, bias_seg, act, cf32);
  dim3 grid(M/128, (N+127)/128, 1);
  gemm_bt<128,128,2,2><<<grid, 256, 0, st>>>(g);
}

// 64x128 tiles for small-N shapes (N=768/1536): doubles workgroup count so the
// grid covers >=192 of 256 CUs instead of 96.
static void gemm64(const u16* A, int lda, const u16* Bt, int ldb, void* C, int ldc,
                   int M, int N, int K, const float* b0, const float* b1, const float* b2,
                   int bias_seg, int act, int cf32, hipStream_t st) {
  GemmArgs g; gemm_args(g, A, lda, Bt, ldb, C, ldc, M, N, K, b0, b1, b2, bias_seg, act, cf32);
  dim3 grid(M/64, (N+127)/128, 1);
  gemm_bt<64,128,1,2><<<grid, 128, 0, st>>>(g);
}

extern "C" void kernel_launch(void* const* d_in, const int* in_sizes, int n_in,
                              void* d_out, int out_size, void* d_ws, size_t ws_size,
                              hipStream_t stream) {
  (void)in_sizes; (void)n_in; (void)out_size;
  const int*   ids  = (const int*)d_in[0];
  const float* enc  = (const float*)d_in[1];
  const float* wemb = (const float*)d_in[2];
  const float* pemb = (const float*)d_in[3];
  const float* temb = (const float*)d_in[4];
  const float* eg   = (const float*)d_in[5];
  const float* eb   = (const float*)d_in[6];
  const float* Wq=(const float*)d_in[7];  const float* bq=(const float*)d_in[8];
  const float* Wk=(const float*)d_in[9];  const float* bk=(const float*)d_in[10];
  const float* Wv=(const float*)d_in[11]; const float* bv=(const float*)d_in[12];
  const float* Wo=(const float*)d_in[13]; const float* bo=(const float*)d_in[14];
  const float* l1g=(const float*)d_in[15]; const float* l1b=(const float*)d_in[16];
  const float* cWq=(const float*)d_in[17]; const float* cbq=(const float*)d_in[18];
  const float* cWk=(const float*)d_in[19]; const float* cbk=(const float*)d_in[20];
  const float* cWv=(const float*)d_in[21]; const float* cbv=(const float*)d_in[22];
  const float* cWo=(const float*)d_in[23]; const float* cbo=(const float*)d_in[24];
  const float* l2g=(const float*)d_in[25]; const float* l2b=(const float*)d_in[26];
  const float* Wi=(const float*)d_in[27];  const float* bi=(const float*)d_in[28];
  const float* Wf=(const float*)d_in[29];  const float* bff=(const float*)d_in[30];
  const float* l3g=(const float*)d_in[31]; const float* l3b=(const float*)d_in[32];
  const float* Wt=(const float*)d_in[33];  const float* bt=(const float*)d_in[34];
  const float* lhg=(const float*)d_in[35]; const float* lhb=(const float*)d_in[36];
  const float* Wdec=(const float*)d_in[37]; const float* bdec=(const float*)d_in[38];
  float* out = (float*)d_out;

  // workspace layout (u16 units)
  u16* ws     = (u16*)d_ws;
  u16* WT     = ws;                          // 24,030,720 u16 (reused per layer / head)
  u16* h_bf   = WT + 24030720;               // 1,572,864 u16
  float* h_f  = (float*)(h_bf + 1572864);    // 1,572,864 f32
  float* h2_f = h_f + 1572864;               // 1,572,864 f32
  u16* qkv    = (u16*)(h2_f + 1572864);      // 4,718,592 u16
  u16* ctx    = qkv + 4718592;               // 1,572,864 u16
  u16* VT     = ctx + 1572864;               // 1,572,864 u16
  u16* enc_bf = VT + 1572864;                // 1,572,864 u16
  u16* Smat   = enc_bf + 1572864;            // 12,582,912 u16
  u16* mid    = Smat;                        // 6,291,456 u16 (FFN only)
  // total = 53,915,136 u16 = 107.8 MB
  if (ws_size < (size_t)53915136 * 2) return;

  const int DD = 589824, DF = 2359296;
  // per-layer WT sub-regions (bf16)
  u16* qkvT = WT;                 // 2304x768
  u16* woT  = WT + 1769472;       // 768x768
  u16* cqT  = WT + 2359296;       // 768x768
  u16* ckvT = WT + 2949120;       // 1536x768
  u16* cwoT = WT + 4128768;       // 768x768
  u16* wiT  = WT + 4718592;       // 3072x768
  u16* wfT  = WT + 7077888;       // 768x3072

  embed_kernel<<<2048, 256, 0, stream>>>(ids, wemb, pemb, temb, eg, eb, h_f, h_bf);
  cvt_kernel<<<1536, 256, 0, stream>>>(enc, enc_bf, 1572864);

  for (int l = 0; l < 6; l++) {
    // transpose+convert this layer's weights
    TransArgs ta; int tile = 0; int idx = 0;
    auto add = [&](const float* s, u16* d, int K, int N) {
      ta.e[idx].src=s; ta.e[idx].dst=d; ta.e[idx].K=K; ta.e[idx].N=N; ta.e[idx].tile0=tile;
      tile += (K/64)*((N+63)/64); idx++;
    };
    add(Wq +(i64)l*DD, qkvT,        768, 768);
    add(Wk +(i64)l*DD, qkvT+DD,     768, 768);
    add(Wv +(i64)l*DD, qkvT+2*DD,   768, 768);
    add(Wo +(i64)l*DD, woT,         768, 768);
    add(cWq+(i64)l*DD, cqT,         768, 768);
    add(cWk+(i64)l*DD, ckvT,        768, 768);
    add(cWv+(i64)l*DD, ckvT+DD,     768, 768);
    add(cWo+(i64)l*DD, cwoT,        768, 768);
    add(Wi +(i64)l*DF, wiT,         768, 3072);
    add(Wf +(i64)l*DF, wfT,         3072, 768);
    ta.n = idx;
    transpose_multi<<<tile, 256, 0, stream>>>(ta);

    // ---- self attention ----
    gemm128(h_bf, 768, qkvT, 768, qkv, 2304, 2048, 2304, 768,
            bq+l*768, bk+l*768, bv+l*768, 768, 0, 0, stream);
    vtrans_kernel<<<dim3(8,1,48), 256, 0, stream>>>(qkv, VT);
    flash_attn<<<dim3(32,48), 64, 0, stream>>>(qkv, VT, ctx, 1);
    gemm64(ctx, 768, woT, 768, h2_f, 768, 2048, 768, 768,
           bo+l*768, nullptr, nullptr, 768, 0, 1, stream);
    resln_kernel<<<2048, 256, 0, stream>>>(h_f, h2_f, l1g+l*768, l1b+l*768, h_f, h_bf);

    // ---- cross attention ----
    gemm64(h_bf, 768, cqT, 768, qkv, 2304, 2048, 768, 768,
           cbq+l*768, nullptr, nullptr, 768, 0, 0, stream);
    gemm64(enc_bf, 768, ckvT, 768, qkv+768, 2304, 2048, 1536, 768,
           cbk+l*768, cbv+l*768, nullptr, 768, 0, 0, stream);
    vtrans_kernel<<<dim3(8,1,48), 256, 0, stream>>>(qkv, VT);
    flash_attn<<<dim3(32,48), 64, 0, stream>>>(qkv, VT, ctx, 0);
    gemm64(ctx, 768, cwoT, 768, h2_f, 768, 2048, 768, 768,
           cbo+l*768, nullptr, nullptr, 768, 0, 1, stream);
    resln_kernel<<<2048, 256, 0, stream>>>(h_f, h2_f, l2g+l*768, l2b+l*768, h_f, h_bf);

    // ---- FFN ----
    gemm128(h_bf, 768, wiT, 768, mid, 3072, 2048, 3072, 768,
            bi+l*3072, nullptr, nullptr, 3072, 1, 0, stream);
    gemm64(mid, 3072, wfT, 3072, h2_f, 768, 2048, 768, 3072,
           bff+l*768, nullptr, nullptr, 768, 0, 1, stream);
    resln_kernel<<<2048, 256, 0, stream>>>(h_f, h2_f, l3g+l*768, l3b+l*768, h_f, h_bf);
  }

  // ---- MLM head ----
  u16* wtT   = WT;            // 768x768
  u16* wdecT = WT + 589824;   // 30522x768
  {
    TransArgs ta; int tile = 0; int idx = 0;
    auto add = [&](const float* s, u16* d, int K, int N) {
      ta.e[idx].src=s; ta.e[idx].dst=d; ta.e[idx].K=K; ta.e[idx].N=N; ta.e[idx].tile0=tile;
      tile += (K/64)*((N+63)/64); idx++;
    };
    add(Wt,   wtT,   768, 768);
    add(Wdec, wdecT, 768, 30522);
    ta.n = idx;
    transpose_multi<<<tile, 256, 0, stream>>>(ta);
  }
  gemm64(h_bf, 768, wtT, 768, h2_f, 768, 2048, 768, 768, bt, nullptr, nullptr, 768, 1, 1, stream);
  resln_kernel<<<2048, 256, 0, stream>>>(nullptr, h2_f, lhg, lhb, h_f, h_bf);
  gemm128(h_bf, 768, wdecT, 768, out, 30522, 2048, 30522, 768,
          bdec, nullptr, nullptr, 30522, 0, 1, stream);
}

// Round 4
// 2532.265 us; speedup vs baseline: 1.2022x; 1.0554x over previous
//
#include <hip/hip_runtime.h>
#include <math.h>

typedef unsigned short u16;
typedef unsigned int   u32;
typedef long long      i64;
typedef __attribute__((ext_vector_type(8))) __bf16 bf16x8;
typedef __attribute__((ext_vector_type(4))) float  f32x4;
typedef __attribute__((ext_vector_type(8))) u16    u16x8;
typedef __attribute__((ext_vector_type(4))) u16    u16x4;

#define LN_EPS 1e-12f

__device__ __forceinline__ float b2f(u16 u){ union {u32 i; float f;} v; v.i = ((u32)u)<<16; return v.f; }
__device__ __forceinline__ u16 f2b(float f){ union {float f; u32 i;} v; v.f = f; u32 r = v.i + 0x7FFFu + ((v.i>>16)&1u); return (u16)(r>>16); }

__device__ __forceinline__ void gl2lds16(const u16* g, u16* l) {
  __builtin_amdgcn_global_load_lds((const __attribute__((address_space(1))) void*)g,
                                   (__attribute__((address_space(3))) void*)l, 16, 0, 0);
}

// ---------------------------------------------------------------- GEMM (B^T), 2-phase dbuf
// C[m][n] = sum_k A[m][k] * Bt[n][k] (+f32 bias, +gelu). A/Bt bf16; C bf16 or f32.
// Schedule: stage(next tile) -> compute(current) -> barrier (drains the prefetch).
// Load latency hides under the MFMA phase (critical at ~1 block/CU grids).
// LDS swizzle: 16B slot index s' = s ^ ((row>>1)&3), applied on BOTH the
// global source of global_load_lds (linear dest) and the ds_read address
// (rule #21: both-sides-or-neither).
struct GemmArgs {
  const u16* A; const u16* Bt; void* C;
  const float* bias0; const float* bias1; const float* bias2;
  int lda, ldb, ldc, M, N, K, bias_seg, act, cf32;
};

template<int BM, int BN, int WM, int WN>
__global__ __launch_bounds__(WM*WN*64)
void gemm_bt2(GemmArgs g) {
  constexpr int NTHR = WM*WN*64;
  constexpr int MI = BM/(WM*16);
  constexpr int NJ = BN/(WN*16);
  constexpr int RA = (BM*4)/NTHR;   // staging rounds for A (NTHR/4 rows per round)
  constexpr int RB = (BN*4)/NTHR;
  __shared__ u16 As[2][BM*32];
  __shared__ u16 Bs[2][BN*32];
  const int tid  = threadIdx.x;
  const int wave = tid >> 6, lane = tid & 63;
  const int wm = wave / WN, wn = wave % WN;
  const int lrow = lane & 15, quad = lane >> 4;

  // XCD-chunked bijective swizzle (m204) — only when the grid is large enough
  // that panel reuse across consecutive blocks exists.
  int bx, by;
  {
    const int gx = gridDim.x;
    const int nwg = gx * gridDim.y;
    const int wg = blockIdx.y * gx + blockIdx.x;
    if (nwg >= 512) {
      const int q = nwg >> 3, r = nwg & 7;
      const int xcd = wg & 7, loc = wg >> 3;
      const int nid = (xcd < r ? xcd * (q + 1) : r * (q + 1) + (xcd - r) * q) + loc;
      bx = nid % gx; by = nid / gx;
    } else { bx = blockIdx.x; by = blockIdx.y; }
  }

  const u16* Ab = g.A + (i64)bx*BM*g.lda;
  const u16* Bt = g.Bt;
  const int n0 = by * BN;

  const int srow = tid >> 2;   // staging: row within round (4 thr x 16B = 64B row)
  const int sps  = tid & 3;    // physical 16B slot within row

  f32x4 acc[MI][NJ];
  #pragma unroll
  for (int i=0;i<MI;i++)
    #pragma unroll
    for (int j=0;j<NJ;j++) acc[i][j] = (f32x4){0.f,0.f,0.f,0.f};

  auto stage = [&](int buf, int k0) {
    #pragma unroll
    for (int la=0; la<RA; ++la) {
      int row = la*(NTHR>>2) + srow;
      int ls = sps ^ ((row>>1)&3);                       // inverse swizzle on source
      const u16* src = Ab + (i64)row*g.lda + k0 + (ls<<3);
      gl2lds16(src, &As[buf][(la*NTHR + (wave<<6))<<3]); // wave-uniform linear dest
    }
    #pragma unroll
    for (int la=0; la<RB; ++la) {
      int row = la*(NTHR>>2) + srow;
      int nrow = n0 + row; if (nrow >= g.N) nrow = g.N-1;  // clamp (stores guarded)
      int ls = sps ^ ((row>>1)&3);
      const u16* src = Bt + (i64)nrow*g.ldb + k0 + (ls<<3);
      gl2lds16(src, &Bs[buf][(la*NTHR + (wave<<6))<<3]);
    }
  };

  const int NT = g.K >> 5;
  stage(0, 0);
  __syncthreads();                 // compiler drains vmcnt before s_barrier
  for (int t = 0; t < NT; ++t) {
    const int cur = t & 1;
    if (t+1 < NT) stage(cur^1, (t+1)<<5);   // prefetch next K-tile (in flight across MFMA)
    const int xr = (lrow>>1)&3;
    bf16x8 a[MI], b[NJ];
    #pragma unroll
    for (int i=0;i<MI;i++) {
      int r = wm*(MI*16) + i*16 + lrow;
      a[i] = *(const bf16x8*)&As[cur][r*32 + ((quad^xr)<<3)];
    }
    #pragma unroll
    for (int j=0;j<NJ;j++) {
      int r = wn*(NJ*16) + j*16 + lrow;
      b[j] = *(const bf16x8*)&Bs[cur][r*32 + ((quad^xr)<<3)];
    }
    #pragma unroll
    for (int i=0;i<MI;i++)
      #pragma unroll
      for (int j=0;j<NJ;j++)
        acc[i][j] = __builtin_amdgcn_mfma_f32_16x16x32_bf16(a[i], b[j], acc[i][j], 0,0,0);
    __syncthreads();               // prefetch drained here; safe to overwrite next iter
  }

  const i64 rowbase = (i64)bx*BM + wm*(MI*16);
  u16*   Cb = (u16*)g.C;
  float* Cf = (float*)g.C;
  #pragma unroll
  for (int i=0;i<MI;i++) {
    #pragma unroll
    for (int j=0;j<NJ;j++) {
      int col = n0 + wn*(NJ*16) + (j<<4) + lrow;
      if (col < g.N) {
        float bias = 0.f;
        if (g.bias0) {
          int seg = col / g.bias_seg;
          const float* bp = (seg==0) ? g.bias0 : ((seg==1) ? g.bias1 : g.bias2);
          bias = bp[col - seg*g.bias_seg];
        }
        #pragma unroll
        for (int r=0;r<4;r++) {
          i64 row = rowbase + (i<<4) + (quad<<2) + r;
          float v = acc[i][j][r] + bias;
          if (g.act == 1) v = 0.5f*v*(1.0f + erff(v*0.70710678118654752f));
          if (g.cf32) Cf[row*(i64)g.ldc + col] = v;
          else        Cb[row*(i64)g.ldc + col] = f2b(v);
        }
      }
    }
  }
}

// ---------------------------------------------------------------- fused flash attention
// One wave (64 thr) per (16 q-rows, b, h). Grid (32, 48). No LDS, no barriers.
__global__ __launch_bounds__(64) void flash_attn(const u16* __restrict__ qkv,
                                                 const u16* __restrict__ VT,
                                                 u16* __restrict__ ctx, int causal) {
  const int lane = threadIdx.x & 63;
  const int qi = lane & 15, g = lane >> 4;
  const int q0 = blockIdx.x << 4;            // 16 q-rows per wave
  const int bh = blockIdx.y;
  const int b = bh / 12, h = bh % 12;
  const int q = q0 + qi;

  const u16* Qp = qkv + (i64)(b*512 + q)*2304 + h*64 + (g<<3);
  bf16x8 qf0 = *(const bf16x8*)Qp;
  bf16x8 qf1 = *(const bf16x8*)(Qp + 32);

  const u16* Kp = qkv + ((i64)(b*512 + qi))*2304 + 768 + h*64 + (g<<3);
  const u16* Vp = VT + (i64)bh*32768 + (i64)qi*512 + (g<<3);

  f32x4 o[4];
  #pragma unroll
  for (int s=0;s<4;s++) o[s] = (f32x4){0.f,0.f,0.f,0.f};
  float m = -1e30f, lsum = 0.f;

  const int sA = qi + ((g & 1) << 5);
  const int sB = sA + 16;
  const int tsel = g >> 1;

  const int nt = causal ? (q0 >> 6) + 1 : 8;
  for (int kt = 0; kt < nt; ++kt) {
    const int kv0 = kt << 6;

    bf16x8 kf[4][2];
    #pragma unroll
    for (int t=0;t<4;t++)
      #pragma unroll
      for (int w=0;w<2;w++)
        kf[t][w] = *(const bf16x8*)(Kp + (i64)(kv0 + (t<<4))*2304 + (w<<5));
    bf16x8 vf[4][2];
    #pragma unroll
    for (int s=0;s<4;s++)
      #pragma unroll
      for (int w=0;w<2;w++)
        vf[s][w] = *(const bf16x8*)(Vp + (s<<13) + kv0 + (w<<5));

    f32x4 sc[4];
    #pragma unroll
    for (int t=0;t<4;t++) {
      sc[t] = (f32x4){0.f,0.f,0.f,0.f};
      sc[t] = __builtin_amdgcn_mfma_f32_16x16x32_bf16(kf[t][0], qf0, sc[t], 0,0,0);
      sc[t] = __builtin_amdgcn_mfma_f32_16x16x32_bf16(kf[t][1], qf1, sc[t], 0,0,0);
    }

    float x[4][4];
    #pragma unroll
    for (int t=0;t<4;t++)
      #pragma unroll
      for (int r=0;r<4;r++) {
        float v = sc[t][r] * 0.125f;
        int key = kv0 + (t<<4) + (g<<2) + r;
        if (causal && key > q) v = -1e30f;
        x[t][r] = v;
      }

    float mt = x[0][0];
    #pragma unroll
    for (int t=0;t<4;t++)
      #pragma unroll
      for (int r=0;r<4;r++) mt = fmaxf(mt, x[t][r]);
    mt = fmaxf(mt, __shfl_xor(mt, 16));
    mt = fmaxf(mt, __shfl_xor(mt, 32));
    float mn = fmaxf(m, mt);
    float c = __expf(m - mn);
    m = mn;

    float p[4][4];
    float ps = 0.f;
    #pragma unroll
    for (int t=0;t<4;t++)
      #pragma unroll
      for (int r=0;r<4;r++) { float e = __expf(x[t][r] - mn); p[t][r] = e; ps += e; }
    ps += __shfl_xor(ps, 16);
    ps += __shfl_xor(ps, 32);
    lsum = lsum * c + ps;
    #pragma unroll
    for (int s=0;s<4;s++) o[s] *= c;

    u32 pkLo[4], pkHi[4];
    #pragma unroll
    for (int t=0;t<4;t++) {
      pkLo[t] = (u32)f2b(p[t][0]) | ((u32)f2b(p[t][1]) << 16);
      pkHi[t] = (u32)f2b(p[t][2]) | ((u32)f2b(p[t][3]) << 16);
    }

    #pragma unroll
    for (int w=0;w<2;w++) {
      u32 w0=0, w1=0, w2=0, w3=0;
      #pragma unroll
      for (int tl=0; tl<2; ++tl) {
        const int t = 2*w + tl;
        u32 aLo = (u32)__shfl((int)pkLo[t], sA);
        u32 aHi = (u32)__shfl((int)pkHi[t], sA);
        u32 bLo = (u32)__shfl((int)pkLo[t], sB);
        u32 bHi = (u32)__shfl((int)pkHi[t], sB);
        if (tsel == tl) { w0=aLo; w1=aHi; w2=bLo; w3=bHi; }
      }
      union { bf16x8 v; u32 u[4]; } pf;
      pf.u[0]=w0; pf.u[1]=w1; pf.u[2]=w2; pf.u[3]=w3;
      #pragma unroll
      for (int s=0;s<4;s++)
        o[s] = __builtin_amdgcn_mfma_f32_16x16x32_bf16(vf[s][w], pf.v, o[s], 0,0,0);
    }
  }

  float inv = 1.0f / lsum;
  u16* orow = ctx + (i64)(b*512 + q)*768 + h*64 + (g<<2);
  #pragma unroll
  for (int s=0;s<4;s++) {
    u16x4 ov;
    #pragma unroll
    for (int r=0;r<4;r++) ov[r] = f2b(o[s][r] * inv);
    *(u16x4*)(orow + (s<<4)) = ov;
  }
}

// ---------------------------------------------------------------- LN helpers
__device__ __forceinline__ float block_reduce_sum_256(float v, float* red) {
  #pragma unroll
  for (int off=32; off; off>>=1) v += __shfl_xor(v, off);
  int wave = threadIdx.x >> 6;
  __syncthreads();
  if ((threadIdx.x & 63) == 0) red[wave] = v;
  __syncthreads();
  return red[0]+red[1]+red[2]+red[3];
}

__global__ __launch_bounds__(256) void resln_kernel(const float* base, const float* delta,
                                                    const float* gam, const float* bet,
                                                    float* out_f, u16* out_b) {
  __shared__ float red[4];
  i64 off = (i64)blockIdx.x * 768;
  int tid = threadIdx.x;
  float x[3];
  #pragma unroll
  for (int j=0;j<3;j++) {
    int i = tid + j*256;
    float v = delta[off+i];
    if (base) v += base[off+i];
    x[j] = v;
  }
  float s = block_reduce_sum_256(x[0]+x[1]+x[2], red);
  float mean = s * (1.0f/768.0f);
  float q = 0.f;
  #pragma unroll
  for (int j=0;j<3;j++) { float d = x[j]-mean; q += d*d; }
  q = block_reduce_sum_256(q, red);
  float r = rsqrtf(q*(1.0f/768.0f) + LN_EPS);
  #pragma unroll
  for (int j=0;j<3;j++) {
    int i = tid + j*256;
    float y = (x[j]-mean)*r*gam[i] + bet[i];
    out_f[off+i] = y;
    out_b[off+i] = f2b(y);
  }
}

__global__ __launch_bounds__(256) void embed_kernel(const int* ids, const float* wemb,
    const float* pemb, const float* temb, const float* gam, const float* bet,
    float* out_f, u16* out_b) {
  __shared__ float red[4];
  int row = blockIdx.x;
  int s = row & 511;
  i64 wrow = (i64)ids[row] * 768;
  i64 off = (i64)row * 768;
  int tid = threadIdx.x;
  float x[3];
  #pragma unroll
  for (int j=0;j<3;j++) {
    int i = tid + j*256;
    x[j] = wemb[wrow+i] + pemb[(i64)s*768+i] + temb[i];
  }
  float sm = block_reduce_sum_256(x[0]+x[1]+x[2], red);
  float mean = sm * (1.0f/768.0f);
  float q = 0.f;
  #pragma unroll
  for (int j=0;j<3;j++) { float d = x[j]-mean; q += d*d; }
  q = block_reduce_sum_256(q, red);
  float r = rsqrtf(q*(1.0f/768.0f) + LN_EPS);
  #pragma unroll
  for (int j=0;j<3;j++) {
    int i = tid + j*256;
    float y = (x[j]-mean)*r*gam[i] + bet[i];
    out_f[off+i] = y;
    out_b[off+i] = f2b(y);
  }
}

__global__ __launch_bounds__(256) void cvt_kernel(const float* src, u16* dst, int n) {
  int i = (blockIdx.x*256 + threadIdx.x) * 4;
  if (i + 3 < n) {
    float4 v = *(const float4*)&src[i];
    dst[i+0]=f2b(v.x); dst[i+1]=f2b(v.y); dst[i+2]=f2b(v.z); dst[i+3]=f2b(v.w);
  }
}

// ---------------------------------------------------------------- transposes
struct TransEntry { const float* src; u16* dst; int K, N, tile0; };
struct TransArgs  { TransEntry e[12]; int n; };

__global__ __launch_bounds__(256) void transpose_multi(TransArgs ta) {
  __shared__ u16 tile[64][72];
  int t = blockIdx.x;
  int ei = 0;
  for (int i=1;i<ta.n;i++) if (t >= ta.e[i].tile0) ei = i;
  TransEntry E = ta.e[ei];
  int lt = t - E.tile0;
  int ntn = (E.N + 63) >> 6;
  int tk = lt / ntn, tn = lt - tk*ntn;
  int tid = threadIdx.x;
  int kk = tid >> 2, c = (tid & 3) << 4;
  i64 gk = (i64)(tk*64 + kk);
  int gn0 = tn*64 + c;
  const float* srow = E.src + gk * E.N;
  if (gn0 + 16 <= E.N) {
    #pragma unroll
    for (int j=0;j<16;j++) tile[kk][c+j] = f2b(srow[gn0+j]);
  } else {
    for (int j=0;j<16;j++) tile[kk][c+j] = (gn0+j < E.N) ? f2b(srow[gn0+j]) : (u16)0;
  }
  __syncthreads();
  int nn = tid >> 2, kc = (tid & 3) << 4;
  int gn = tn*64 + nn;
  if (gn < E.N) {
    u16x8 v0, v1;
    #pragma unroll
    for (int j=0;j<8;j++) { v0[j] = tile[kc+j][nn]; v1[j] = tile[kc+8+j][nn]; }
    u16* drow = E.dst + (i64)gn*E.K + tk*64 + kc;
    *(u16x8*)&drow[0] = v0;
    *(u16x8*)&drow[8] = v1;
  }
}

// VT[bh][d][key] = qkv[b*512+key][1536 + h*64 + d]   (bf16 -> bf16)
__global__ __launch_bounds__(256) void vtrans_kernel(const u16* qkv, u16* VT) {
  __shared__ u16 tile[64][72];
  int bh = blockIdx.z; int b = bh / 12, hh = bh % 12;
  const u16* src = qkv + (i64)b*512*2304 + 1536 + hh*64;
  u16* dst = VT + (i64)bh*64*512;
  int kt = blockIdx.x;
  int tid = threadIdx.x;
  int kk = tid >> 2, c = (tid & 3) << 4;
  const u32* p = (const u32*)&src[(i64)(kt*64+kk)*2304 + c];
  #pragma unroll
  for (int j=0;j<8;j++) *(u32*)&tile[kk][c + 2*j] = p[j];
  __syncthreads();
  int dd = tid >> 2, kc = (tid & 3) << 4;
  u16x8 v0, v1;
  #pragma unroll
  for (int j=0;j<8;j++) { v0[j] = tile[kc+j][dd]; v1[j] = tile[kc+8+j][dd]; }
  u16* drow = dst + (i64)dd*512 + kt*64 + kc;
  *(u16x8*)&drow[0] = v0;
  *(u16x8*)&drow[8] = v1;
}

// ---------------------------------------------------------------- host side
static void gemm_args(GemmArgs& g, const u16* A, int lda, const u16* Bt, int ldb,
                      void* C, int ldc, int M, int N, int K, const float* b0,
                      const float* b1, const float* b2, int bias_seg, int act, int cf32) {
  g.A=A; g.Bt=Bt; g.C=C; g.bias0=b0; g.bias1=b1; g.bias2=b2;
  g.lda=lda; g.ldb=ldb; g.ldc=ldc; g.M=M; g.N=N; g.K=K;
  g.bias_seg=bias_seg; g.act=act; g.cf32=cf32;
}

static void g2_128(const u16* A, int lda, const u16* Bt, int ldb, void* C, int ldc,
                   int M, int N, int K, const float* b0, const float* b1, const float* b2,
                   int bias_seg, int act, int cf32, hipStream_t st) {
  GemmArgs g; gemm_args(g, A, lda, Bt, ldb, C, ldc, M, N, K, b0, b1, b2, bias_seg, act, cf32);
  gemm_bt2<128,128,2,2><<<dim3(M/128, (N+127)/128), 256, 0, st>>>(g);
}

static void g2_64(const u16* A, int lda, const u16* Bt, int ldb, void* C, int ldc,
                  int M, int N, int K, const float* b0, const float* b1, const float* b2,
                  int bias_seg, int act, int cf32, hipStream_t st) {
  GemmArgs g; gemm_args(g, A, lda, Bt, ldb, C, ldc, M, N, K, b0, b1, b2, bias_seg, act, cf32);
  gemm_bt2<64,128,1,2><<<dim3(M/64, (N+127)/128), 128, 0, st>>>(g);
}

static void g2_256(const u16* A, int lda, const u16* Bt, int ldb, void* C, int ldc,
                   int M, int N, int K, const float* b0, const float* b1, const float* b2,
                   int bias_seg, int act, int cf32, hipStream_t st) {
  GemmArgs g; gemm_args(g, A, lda, Bt, ldb, C, ldc, M, N, K, b0, b1, b2, bias_seg, act, cf32);
  gemm_bt2<256,256,2,4><<<dim3(M/256, (N+255)/256), 512, 0, st>>>(g);
}

extern "C" void kernel_launch(void* const* d_in, const int* in_sizes, int n_in,
                              void* d_out, int out_size, void* d_ws, size_t ws_size,
                              hipStream_t stream) {
  (void)in_sizes; (void)n_in; (void)out_size;
  const int*   ids  = (const int*)d_in[0];
  const float* enc  = (const float*)d_in[1];
  const float* wemb = (const float*)d_in[2];
  const float* pemb = (const float*)d_in[3];
  const float* temb = (const float*)d_in[4];
  const float* eg   = (const float*)d_in[5];
  const float* eb   = (const float*)d_in[6];
  const float* Wq=(const float*)d_in[7];  const float* bq=(const float*)d_in[8];
  const float* Wk=(const float*)d_in[9];  const float* bk=(const float*)d_in[10];
  const float* Wv=(const float*)d_in[11]; const float* bv=(const float*)d_in[12];
  const float* Wo=(const float*)d_in[13]; const float* bo=(const float*)d_in[14];
  const float* l1g=(const float*)d_in[15]; const float* l1b=(const float*)d_in[16];
  const float* cWq=(const float*)d_in[17]; const float* cbq=(const float*)d_in[18];
  const float* cWk=(const float*)d_in[19]; const float* cbk=(const float*)d_in[20];
  const float* cWv=(const float*)d_in[21]; const float* cbv=(const float*)d_in[22];
  const float* cWo=(const float*)d_in[23]; const float* cbo=(const float*)d_in[24];
  const float* l2g=(const float*)d_in[25]; const float* l2b=(const float*)d_in[26];
  const float* Wi=(const float*)d_in[27];  const float* bi=(const float*)d_in[28];
  const float* Wf=(const float*)d_in[29];  const float* bff=(const float*)d_in[30];
  const float* l3g=(const float*)d_in[31]; const float* l3b=(const float*)d_in[32];
  const float* Wt=(const float*)d_in[33];  const float* bt=(const float*)d_in[34];
  const float* lhg=(const float*)d_in[35]; const float* lhb=(const float*)d_in[36];
  const float* Wdec=(const float*)d_in[37]; const float* bdec=(const float*)d_in[38];
  float* out = (float*)d_out;

  // workspace layout (u16 units)
  u16* ws     = (u16*)d_ws;
  u16* WT     = ws;                          // 24,030,720 u16 (reused per layer / head)
  u16* h_bf   = WT + 24030720;               // 1,572,864 u16
  float* h_f  = (float*)(h_bf + 1572864);    // 1,572,864 f32
  float* h2_f = h_f + 1572864;               // 1,572,864 f32
  u16* qkv    = (u16*)(h2_f + 1572864);      // 4,718,592 u16
  u16* ctx    = qkv + 4718592;               // 1,572,864 u16
  u16* VT     = ctx + 1572864;               // 1,572,864 u16
  u16* enc_bf = VT + 1572864;                // 1,572,864 u16
  u16* Smat   = enc_bf + 1572864;            // 12,582,912 u16
  u16* mid    = Smat;                        // 6,291,456 u16 (FFN only)
  if (ws_size < (size_t)53915136 * 2) return;

  const int DD = 589824, DF = 2359296;
  u16* qkvT = WT;                 // 2304x768
  u16* woT  = WT + 1769472;       // 768x768
  u16* cqT  = WT + 2359296;       // 768x768
  u16* ckvT = WT + 2949120;       // 1536x768
  u16* cwoT = WT + 4128768;       // 768x768
  u16* wiT  = WT + 4718592;       // 3072x768
  u16* wfT  = WT + 7077888;       // 768x3072

  embed_kernel<<<2048, 256, 0, stream>>>(ids, wemb, pemb, temb, eg, eb, h_f, h_bf);
  cvt_kernel<<<1536, 256, 0, stream>>>(enc, enc_bf, 1572864);

  for (int l = 0; l < 6; l++) {
    TransArgs ta; int tile = 0; int idx = 0;
    auto add = [&](const float* s, u16* d, int K, int N) {
      ta.e[idx].src=s; ta.e[idx].dst=d; ta.e[idx].K=K; ta.e[idx].N=N; ta.e[idx].tile0=tile;
      tile += (K/64)*((N+63)/64); idx++;
    };
    add(Wq +(i64)l*DD, qkvT,        768, 768);
    add(Wk +(i64)l*DD, qkvT+DD,     768, 768);
    add(Wv +(i64)l*DD, qkvT+2*DD,   768, 768);
    add(Wo +(i64)l*DD, woT,         768, 768);
    add(cWq+(i64)l*DD, cqT,         768, 768);
    add(cWk+(i64)l*DD, ckvT,        768, 768);
    add(cWv+(i64)l*DD, ckvT+DD,     768, 768);
    add(cWo+(i64)l*DD, cwoT,        768, 768);
    add(Wi +(i64)l*DF, wiT,         768, 3072);
    add(Wf +(i64)l*DF, wfT,         3072, 768);
    ta.n = idx;
    transpose_multi<<<tile, 256, 0, stream>>>(ta);

    // ---- self attention ----
    g2_128(h_bf, 768, qkvT, 768, qkv, 2304, 2048, 2304, 768,
           bq+l*768, bk+l*768, bv+l*768, 768, 0, 0, stream);
    vtrans_kernel<<<dim3(8,1,48), 256, 0, stream>>>(qkv, VT);
    flash_attn<<<dim3(32,48), 64, 0, stream>>>(qkv, VT, ctx, 1);
    g2_64(ctx, 768, woT, 768, h2_f, 768, 2048, 768, 768,
          bo+l*768, nullptr, nullptr, 768, 0, 1, stream);
    resln_kernel<<<2048, 256, 0, stream>>>(h_f, h2_f, l1g+l*768, l1b+l*768, h_f, h_bf);

    // ---- cross attention ----
    g2_64(h_bf, 768, cqT, 768, qkv, 2304, 2048, 768, 768,
          cbq+l*768, nullptr, nullptr, 768, 0, 0, stream);
    g2_64(enc_bf, 768, ckvT, 768, qkv+768, 2304, 2048, 1536, 768,
          cbk+l*768, cbv+l*768, nullptr, 768, 0, 0, stream);
    vtrans_kernel<<<dim3(8,1,48), 256, 0, stream>>>(qkv, VT);
    flash_attn<<<dim3(32,48), 64, 0, stream>>>(qkv, VT, ctx, 0);
    g2_64(ctx, 768, cwoT, 768, h2_f, 768, 2048, 768, 768,
          cbo+l*768, nullptr, nullptr, 768, 0, 1, stream);
    resln_kernel<<<2048, 256, 0, stream>>>(h_f, h2_f, l2g+l*768, l2b+l*768, h_f, h_bf);

    // ---- FFN ----
    g2_128(h_bf, 768, wiT, 768, mid, 3072, 2048, 3072, 768,
           bi+l*3072, nullptr, nullptr, 3072, 1, 0, stream);
    g2_64(mid, 3072, wfT, 3072, h2_f, 768, 2048, 768, 3072,
          bff+l*768, nullptr, nullptr, 768, 0, 1, stream);
    resln_kernel<<<2048, 256, 0, stream>>>(h_f, h2_f, l3g+l*768, l3b+l*768, h_f, h_bf);
  }

  // ---- MLM head ----
  u16* wtT   = WT;            // 768x768
  u16* wdecT = WT + 589824;   // 30522x768
  {
    TransArgs ta; int tile = 0; int idx = 0;
    auto add = [&](const float* s, u16* d, int K, int N) {
      ta.e[idx].src=s; ta.e[idx].dst=d; ta.e[idx].K=K; ta.e[idx].N=N; ta.e[idx].tile0=tile;
      tile += (K/64)*((N+63)/64); idx++;
    };
    add(Wt,   wtT,   768, 768);
    add(Wdec, wdecT, 768, 30522);
    ta.n = idx;
    transpose_multi<<<tile, 256, 0, stream>>>(ta);
  }
  g2_64(h_bf, 768, wtT, 768, h2_f, 768, 2048, 768, 768, bt, nullptr, nullptr, 768, 1, 1, stream);
  resln_kernel<<<2048, 256, 0, stream>>>(nullptr, h2_f, lhg, lhb, h_f, h_bf);
  g2_256(h_bf, 768, wdecT, 768, out, 30522, 2048, 30522, 768,
         bdec, nullptr, nullptr, 30522, 0, 1, stream);
}

// Round 5
// 2506.688 us; speedup vs baseline: 1.2144x; 1.0102x over previous
//
#include <hip/hip_runtime.h>
#include <math.h>

typedef unsigned short u16;
typedef unsigned int   u32;
typedef long long      i64;
typedef __attribute__((ext_vector_type(8))) __bf16 bf16x8;
typedef __attribute__((ext_vector_type(4))) float  f32x4;
typedef __attribute__((ext_vector_type(8))) u16    u16x8;
typedef __attribute__((ext_vector_type(4))) u16    u16x4;

#define LN_EPS 1e-12f

__device__ __forceinline__ float b2f(u16 u){ union {u32 i; float f;} v; v.i = ((u32)u)<<16; return v.f; }
__device__ __forceinline__ u16 f2b(float f){ union {float f; u32 i;} v; v.f = f; u32 r = v.i + 0x7FFFu + ((v.i>>16)&1u); return (u16)(r>>16); }

__device__ __forceinline__ void gl2lds16(const u16* g, u16* l) {
  __builtin_amdgcn_global_load_lds((const __attribute__((address_space(1))) void*)g,
                                   (__attribute__((address_space(3))) void*)l, 16, 0, 0);
}

template<int N> __device__ __forceinline__ void vm_wait() {
  asm volatile("s_waitcnt vmcnt(%0)" :: "i"(N) : "memory");
}
__device__ __forceinline__ void lgkm0() {
  asm volatile("s_waitcnt lgkmcnt(0)" ::: "memory");
}

// ---------------------------------------------------------------- GEMM (B^T), 3-buf 2-deep
// C[m][n] = sum_k A[m][k] * Bt[n][k] (+f32 bias, +gelu). A/Bt bf16; C bf16 or f32.
// Pipeline (T4 counted-vmcnt, m201/m218 pattern):
//   per K-step: stage(t+2) -> vmcnt(2L) [batch t drained, t+1/t+2 in flight]
//   -> s_barrier -> ds_read(cur) -> lgkmcnt(0) -> s_barrier -> MFMA.
// Loads get ~2 compute phases of flight time; vmcnt never drains to 0 mid-loop.
// LDS swizzle: 16B slot s' = s ^ ((row>>1)&3) on BOTH gload source and ds_read
// (rule #21); verified conflict-free in R4 (SQ_LDS_BANK_CONFLICT = 0).
struct GemmArgs {
  const u16* A; const u16* Bt; void* C;
  const float* bias0; const float* bias1; const float* bias2;
  int lda, ldb, ldc, M, N, K, bias_seg, act, cf32;
};

template<int BM, int BN, int WM, int WN>
__global__ __launch_bounds__(WM*WN*64)
void gemm_bt3(GemmArgs g) {
  constexpr int NTHR = WM*WN*64;
  constexpr int MI = BM/(WM*16);
  constexpr int NJ = BN/(WN*16);
  constexpr int RA = (BM*4)/NTHR;   // staging rounds for A (NTHR/4 rows per round)
  constexpr int RB = (BN*4)/NTHR;
  constexpr int L  = RA+RB;         // vmem instrs per wave per stage batch
  __shared__ u16 As[3][BM*32];
  __shared__ u16 Bs[3][BN*32];
  const int tid  = threadIdx.x;
  const int wave = tid >> 6, lane = tid & 63;
  const int wm = wave / WN, wn = wave % WN;
  const int lrow = lane & 15, quad = lane >> 4;

  // XCD-chunked bijective swizzle (m204) for large grids.
  int bx, by;
  {
    const int gx = gridDim.x;
    const int nwg = gx * gridDim.y;
    const int wg = blockIdx.y * gx + blockIdx.x;
    if (nwg >= 512) {
      const int q = nwg >> 3, r = nwg & 7;
      const int xcd = wg & 7, loc = wg >> 3;
      const int nid = (xcd < r ? xcd * (q + 1) : r * (q + 1) + (xcd - r) * q) + loc;
      bx = nid % gx; by = nid / gx;
    } else { bx = blockIdx.x; by = blockIdx.y; }
  }

  const u16* Ab = g.A + (i64)bx*BM*g.lda;
  const u16* Bt = g.Bt;
  const int n0 = by * BN;

  const int srow = tid >> 2;   // staging: row within round
  const int sps  = tid & 3;    // physical 16B slot within 64B row

  f32x4 acc[MI][NJ];
  #pragma unroll
  for (int i=0;i<MI;i++)
    #pragma unroll
    for (int j=0;j<NJ;j++) acc[i][j] = (f32x4){0.f,0.f,0.f,0.f};

  auto stage = [&](int buf, int k0) {
    #pragma unroll
    for (int la=0; la<RA; ++la) {
      int row = la*(NTHR>>2) + srow;
      int ls = sps ^ ((row>>1)&3);                       // inverse swizzle on source
      const u16* src = Ab + (i64)row*g.lda + k0 + (ls<<3);
      gl2lds16(src, &As[buf][(la*NTHR + (wave<<6))<<3]); // wave-uniform linear dest
    }
    #pragma unroll
    for (int la=0; la<RB; ++la) {
      int row = la*(NTHR>>2) + srow;
      int nrow = n0 + row; if (nrow >= g.N) nrow = g.N-1;  // clamp (stores guarded)
      int ls = sps ^ ((row>>1)&3);
      const u16* src = Bt + (i64)nrow*g.ldb + k0 + (ls<<3);
      gl2lds16(src, &Bs[buf][(la*NTHR + (wave<<6))<<3]);
    }
  };

  const int NT = g.K >> 5;
  stage(0, 0);
  if (NT > 1) stage(1, 32);
  for (int t = 0; t < NT; ++t) {
    const int cur = t % 3;
    if (t+2 < NT) { stage((t+2)%3, (t+2)<<5); vm_wait<2*L>(); }
    else if (t+1 < NT) { vm_wait<L>(); }
    else { vm_wait<0>(); }
    __builtin_amdgcn_s_barrier();           // everyone's batch-t data in LDS
    __builtin_amdgcn_sched_barrier(0);
    const int xr = (lrow>>1)&3;
    bf16x8 a[MI], b[NJ];
    #pragma unroll
    for (int i=0;i<MI;i++) {
      int r = wm*(MI*16) + i*16 + lrow;
      a[i] = *(const bf16x8*)&As[cur][r*32 + ((quad^xr)<<3)];
    }
    #pragma unroll
    for (int j=0;j<NJ;j++) {
      int r = wn*(NJ*16) + j*16 + lrow;
      b[j] = *(const bf16x8*)&Bs[cur][r*32 + ((quad^xr)<<3)];
    }
    lgkm0();                                // my reads complete (LDS-only wait)
    __builtin_amdgcn_s_barrier();           // all reads done -> buffer may be restaged
    __builtin_amdgcn_sched_barrier(0);
    #pragma unroll
    for (int i=0;i<MI;i++)
      #pragma unroll
      for (int j=0;j<NJ;j++)
        acc[i][j] = __builtin_amdgcn_mfma_f32_16x16x32_bf16(a[i], b[j], acc[i][j], 0,0,0);
  }

  const i64 rowbase = (i64)bx*BM + wm*(MI*16);
  u16*   Cb = (u16*)g.C;
  float* Cf = (float*)g.C;
  #pragma unroll
  for (int i=0;i<MI;i++) {
    #pragma unroll
    for (int j=0;j<NJ;j++) {
      int col = n0 + wn*(NJ*16) + (j<<4) + lrow;
      if (col < g.N) {
        float bias = 0.f;
        if (g.bias0) {
          int seg = col / g.bias_seg;
          const float* bp = (seg==0) ? g.bias0 : ((seg==1) ? g.bias1 : g.bias2);
          bias = bp[col - seg*g.bias_seg];
        }
        #pragma unroll
        for (int r=0;r<4;r++) {
          i64 row = rowbase + (i<<4) + (quad<<2) + r;
          float v = acc[i][j][r] + bias;
          if (g.act == 1) v = 0.5f*v*(1.0f + erff(v*0.70710678118654752f));
          if (g.cf32) Cf[row*(i64)g.ldc + col] = v;
          else        Cb[row*(i64)g.ldc + col] = f2b(v);
        }
      }
    }
  }
}

// ---------------------------------------------------------------- fused flash attention
// One wave (64 thr) per (16 q-rows, b, h). Grid (32, 48). No LDS, no barriers.
__global__ __launch_bounds__(64) void flash_attn(const u16* __restrict__ qkv,
                                                 const u16* __restrict__ VT,
                                                 u16* __restrict__ ctx, int causal) {
  const int lane = threadIdx.x & 63;
  const int qi = lane & 15, g = lane >> 4;
  const int q0 = blockIdx.x << 4;            // 16 q-rows per wave
  const int bh = blockIdx.y;
  const int b = bh / 12, h = bh % 12;
  const int q = q0 + qi;

  const u16* Qp = qkv + (i64)(b*512 + q)*2304 + h*64 + (g<<3);
  bf16x8 qf0 = *(const bf16x8*)Qp;
  bf16x8 qf1 = *(const bf16x8*)(Qp + 32);

  const u16* Kp = qkv + ((i64)(b*512 + qi))*2304 + 768 + h*64 + (g<<3);
  const u16* Vp = VT + (i64)bh*32768 + (i64)qi*512 + (g<<3);

  f32x4 o[4];
  #pragma unroll
  for (int s=0;s<4;s++) o[s] = (f32x4){0.f,0.f,0.f,0.f};
  float m = -1e30f, lsum = 0.f;

  const int sA = qi + ((g & 1) << 5);
  const int sB = sA + 16;
  const int tsel = g >> 1;

  const int nt = causal ? (q0 >> 6) + 1 : 8;
  for (int kt = 0; kt < nt; ++kt) {
    const int kv0 = kt << 6;

    bf16x8 kf[4][2];
    #pragma unroll
    for (int t=0;t<4;t++)
      #pragma unroll
      for (int w=0;w<2;w++)
        kf[t][w] = *(const bf16x8*)(Kp + (i64)(kv0 + (t<<4))*2304 + (w<<5));
    bf16x8 vf[4][2];
    #pragma unroll
    for (int s=0;s<4;s++)
      #pragma unroll
      for (int w=0;w<2;w++)
        vf[s][w] = *(const bf16x8*)(Vp + (s<<13) + kv0 + (w<<5));

    f32x4 sc[4];
    #pragma unroll
    for (int t=0;t<4;t++) {
      sc[t] = (f32x4){0.f,0.f,0.f,0.f};
      sc[t] = __builtin_amdgcn_mfma_f32_16x16x32_bf16(kf[t][0], qf0, sc[t], 0,0,0);
      sc[t] = __builtin_amdgcn_mfma_f32_16x16x32_bf16(kf[t][1], qf1, sc[t], 0,0,0);
    }

    float x[4][4];
    #pragma unroll
    for (int t=0;t<4;t++)
      #pragma unroll
      for (int r=0;r<4;r++) {
        float v = sc[t][r] * 0.125f;
        int key = kv0 + (t<<4) + (g<<2) + r;
        if (causal && key > q) v = -1e30f;
        x[t][r] = v;
      }

    float mt = x[0][0];
    #pragma unroll
    for (int t=0;t<4;t++)
      #pragma unroll
      for (int r=0;r<4;r++) mt = fmaxf(mt, x[t][r]);
    mt = fmaxf(mt, __shfl_xor(mt, 16));
    mt = fmaxf(mt, __shfl_xor(mt, 32));
    float mn = fmaxf(m, mt);
    float c = __expf(m - mn);
    m = mn;

    float p[4][4];
    float ps = 0.f;
    #pragma unroll
    for (int t=0;t<4;t++)
      #pragma unroll
      for (int r=0;r<4;r++) { float e = __expf(x[t][r] - mn); p[t][r] = e; ps += e; }
    ps += __shfl_xor(ps, 16);
    ps += __shfl_xor(ps, 32);
    lsum = lsum * c + ps;
    #pragma unroll
    for (int s=0;s<4;s++) o[s] *= c;

    u32 pkLo[4], pkHi[4];
    #pragma unroll
    for (int t=0;t<4;t++) {
      pkLo[t] = (u32)f2b(p[t][0]) | ((u32)f2b(p[t][1]) << 16);
      pkHi[t] = (u32)f2b(p[t][2]) | ((u32)f2b(p[t][3]) << 16);
    }

    #pragma unroll
    for (int w=0;w<2;w++) {
      u32 w0=0, w1=0, w2=0, w3=0;
      #pragma unroll
      for (int tl=0; tl<2; ++tl) {
        const int t = 2*w + tl;
        u32 aLo = (u32)__shfl((int)pkLo[t], sA);
        u32 aHi = (u32)__shfl((int)pkHi[t], sA);
        u32 bLo = (u32)__shfl((int)pkLo[t], sB);
        u32 bHi = (u32)__shfl((int)pkHi[t], sB);
        if (tsel == tl) { w0=aLo; w1=aHi; w2=bLo; w3=bHi; }
      }
      union { bf16x8 v; u32 u[4]; } pf;
      pf.u[0]=w0; pf.u[1]=w1; pf.u[2]=w2; pf.u[3]=w3;
      #pragma unroll
      for (int s=0;s<4;s++)
        o[s] = __builtin_amdgcn_mfma_f32_16x16x32_bf16(vf[s][w], pf.v, o[s], 0,0,0);
    }
  }

  float inv = 1.0f / lsum;
  u16* orow = ctx + (i64)(b*512 + q)*768 + h*64 + (g<<2);
  #pragma unroll
  for (int s=0;s<4;s++) {
    u16x4 ov;
    #pragma unroll
    for (int r=0;r<4;r++) ov[r] = f2b(o[s][r] * inv);
    *(u16x4*)(orow + (s<<4)) = ov;
  }
}

// ---------------------------------------------------------------- LN helpers
__device__ __forceinline__ float block_reduce_sum_256(float v, float* red) {
  #pragma unroll
  for (int off=32; off; off>>=1) v += __shfl_xor(v, off);
  int wave = threadIdx.x >> 6;
  __syncthreads();
  if ((threadIdx.x & 63) == 0) red[wave] = v;
  __syncthreads();
  return red[0]+red[1]+red[2]+red[3];
}

__global__ __launch_bounds__(256) void resln_kernel(const float* base, const float* delta,
                                                    const float* gam, const float* bet,
                                                    float* out_f, u16* out_b) {
  __shared__ float red[4];
  i64 off = (i64)blockIdx.x * 768;
  int tid = threadIdx.x;
  float x[3];
  #pragma unroll
  for (int j=0;j<3;j++) {
    int i = tid + j*256;
    float v = delta[off+i];
    if (base) v += base[off+i];
    x[j] = v;
  }
  float s = block_reduce_sum_256(x[0]+x[1]+x[2], red);
  float mean = s * (1.0f/768.0f);
  float q = 0.f;
  #pragma unroll
  for (int j=0;j<3;j++) { float d = x[j]-mean; q += d*d; }
  q = block_reduce_sum_256(q, red);
  float r = rsqrtf(q*(1.0f/768.0f) + LN_EPS);
  #pragma unroll
  for (int j=0;j<3;j++) {
    int i = tid + j*256;
    float y = (x[j]-mean)*r*gam[i] + bet[i];
    out_f[off+i] = y;
    out_b[off+i] = f2b(y);
  }
}

__global__ __launch_bounds__(256) void embed_kernel(const int* ids, const float* wemb,
    const float* pemb, const float* temb, const float* gam, const float* bet,
    float* out_f, u16* out_b) {
  __shared__ float red[4];
  int row = blockIdx.x;
  int s = row & 511;
  i64 wrow = (i64)ids[row] * 768;
  i64 off = (i64)row * 768;
  int tid = threadIdx.x;
  float x[3];
  #pragma unroll
  for (int j=0;j<3;j++) {
    int i = tid + j*256;
    x[j] = wemb[wrow+i] + pemb[(i64)s*768+i] + temb[i];
  }
  float sm = block_reduce_sum_256(x[0]+x[1]+x[2], red);
  float mean = sm * (1.0f/768.0f);
  float q = 0.f;
  #pragma unroll
  for (int j=0;j<3;j++) { float d = x[j]-mean; q += d*d; }
  q = block_reduce_sum_256(q, red);
  float r = rsqrtf(q*(1.0f/768.0f) + LN_EPS);
  #pragma unroll
  for (int j=0;j<3;j++) {
    int i = tid + j*256;
    float y = (x[j]-mean)*r*gam[i] + bet[i];
    out_f[off+i] = y;
    out_b[off+i] = f2b(y);
  }
}

__global__ __launch_bounds__(256) void cvt_kernel(const float* src, u16* dst, int n) {
  int i = (blockIdx.x*256 + threadIdx.x) * 4;
  if (i + 3 < n) {
    float4 v = *(const float4*)&src[i];
    dst[i+0]=f2b(v.x); dst[i+1]=f2b(v.y); dst[i+2]=f2b(v.z); dst[i+3]=f2b(v.w);
  }
}

// ---------------------------------------------------------------- transposes
struct TransEntry { const float* src; u16* dst; int K, N, tile0; };
struct TransArgs  { TransEntry e[12]; int n; };

__global__ __launch_bounds__(256) void transpose_multi(TransArgs ta) {
  __shared__ u16 tile[64][72];
  int t = blockIdx.x;
  int ei = 0;
  for (int i=1;i<ta.n;i++) if (t >= ta.e[i].tile0) ei = i;
  TransEntry E = ta.e[ei];
  int lt = t - E.tile0;
  int ntn = (E.N + 63) >> 6;
  int tk = lt / ntn, tn = lt - tk*ntn;
  int tid = threadIdx.x;
  int kk = tid >> 2, c = (tid & 3) << 4;
  i64 gk = (i64)(tk*64 + kk);
  int gn0 = tn*64 + c;
  const float* srow = E.src + gk * E.N;
  if (gn0 + 16 <= E.N) {
    #pragma unroll
    for (int j=0;j<16;j++) tile[kk][c+j] = f2b(srow[gn0+j]);
  } else {
    for (int j=0;j<16;j++) tile[kk][c+j] = (gn0+j < E.N) ? f2b(srow[gn0+j]) : (u16)0;
  }
  __syncthreads();
  int nn = tid >> 2, kc = (tid & 3) << 4;
  int gn = tn*64 + nn;
  if (gn < E.N) {
    u16x8 v0, v1;
    #pragma unroll
    for (int j=0;j<8;j++) { v0[j] = tile[kc+j][nn]; v1[j] = tile[kc+8+j][nn]; }
    u16* drow = E.dst + (i64)gn*E.K + tk*64 + kc;
    *(u16x8*)&drow[0] = v0;
    *(u16x8*)&drow[8] = v1;
  }
}

// VT[bh][d][key] = qkv[b*512+key][1536 + h*64 + d]   (bf16 -> bf16)
__global__ __launch_bounds__(256) void vtrans_kernel(const u16* qkv, u16* VT) {
  __shared__ u16 tile[64][72];
  int bh = blockIdx.z; int b = bh / 12, hh = bh % 12;
  const u16* src = qkv + (i64)b*512*2304 + 1536 + hh*64;
  u16* dst = VT + (i64)bh*64*512;
  int kt = blockIdx.x;
  int tid = threadIdx.x;
  int kk = tid >> 2, c = (tid & 3) << 4;
  const u32* p = (const u32*)&src[(i64)(kt*64+kk)*2304 + c];
  #pragma unroll
  for (int j=0;j<8;j++) *(u32*)&tile[kk][c + 2*j] = p[j];
  __syncthreads();
  int dd = tid >> 2, kc = (tid & 3) << 4;
  u16x8 v0, v1;
  #pragma unroll
  for (int j=0;j<8;j++) { v0[j] = tile[kc+j][dd]; v1[j] = tile[kc+8+j][dd]; }
  u16* drow = dst + (i64)dd*512 + kt*64 + kc;
  *(u16x8*)&drow[0] = v0;
  *(u16x8*)&drow[8] = v1;
}

// ---------------------------------------------------------------- host side
static void gemm_args(GemmArgs& g, const u16* A, int lda, const u16* Bt, int ldb,
                      void* C, int ldc, int M, int N, int K, const float* b0,
                      const float* b1, const float* b2, int bias_seg, int act, int cf32) {
  g.A=A; g.Bt=Bt; g.C=C; g.bias0=b0; g.bias1=b1; g.bias2=b2;
  g.lda=lda; g.ldb=ldb; g.ldc=ldc; g.M=M; g.N=N; g.K=K;
  g.bias_seg=bias_seg; g.act=act; g.cf32=cf32;
}

static void g3_128(const u16* A, int lda, const u16* Bt, int ldb, void* C, int ldc,
                   int M, int N, int K, const float* b0, const float* b1, const float* b2,
                   int bias_seg, int act, int cf32, hipStream_t st) {
  GemmArgs g; gemm_args(g, A, lda, Bt, ldb, C, ldc, M, N, K, b0, b1, b2, bias_seg, act, cf32);
  gemm_bt3<128,128,2,2><<<dim3(M/128, (N+127)/128), 256, 0, st>>>(g);
}

static void g3_64(const u16* A, int lda, const u16* Bt, int ldb, void* C, int ldc,
                  int M, int N, int K, const float* b0, const float* b1, const float* b2,
                  int bias_seg, int act, int cf32, hipStream_t st) {
  GemmArgs g; gemm_args(g, A, lda, Bt, ldb, C, ldc, M, N, K, b0, b1, b2, bias_seg, act, cf32);
  gemm_bt3<64,128,1,2><<<dim3(M/64, (N+127)/128), 128, 0, st>>>(g);
}

extern "C" void kernel_launch(void* const* d_in, const int* in_sizes, int n_in,
                              void* d_out, int out_size, void* d_ws, size_t ws_size,
                              hipStream_t stream) {
  (void)in_sizes; (void)n_in; (void)out_size;
  const int*   ids  = (const int*)d_in[0];
  const float* enc  = (const float*)d_in[1];
  const float* wemb = (const float*)d_in[2];
  const float* pemb = (const float*)d_in[3];
  const float* temb = (const float*)d_in[4];
  const float* eg   = (const float*)d_in[5];
  const float* eb   = (const float*)d_in[6];
  const float* Wq=(const float*)d_in[7];  const float* bq=(const float*)d_in[8];
  const float* Wk=(const float*)d_in[9];  const float* bk=(const float*)d_in[10];
  const float* Wv=(const float*)d_in[11]; const float* bv=(const float*)d_in[12];
  const float* Wo=(const float*)d_in[13]; const float* bo=(const float*)d_in[14];
  const float* l1g=(const float*)d_in[15]; const float* l1b=(const float*)d_in[16];
  const float* cWq=(const float*)d_in[17]; const float* cbq=(const float*)d_in[18];
  const float* cWk=(const float*)d_in[19]; const float* cbk=(const float*)d_in[20];
  const float* cWv=(const float*)d_in[21]; const float* cbv=(const float*)d_in[22];
  const float* cWo=(const float*)d_in[23]; const float* cbo=(const float*)d_in[24];
  const float* l2g=(const float*)d_in[25]; const float* l2b=(const float*)d_in[26];
  const float* Wi=(const float*)d_in[27];  const float* bi=(const float*)d_in[28];
  const float* Wf=(const float*)d_in[29];  const float* bff=(const float*)d_in[30];
  const float* l3g=(const float*)d_in[31]; const float* l3b=(const float*)d_in[32];
  const float* Wt=(const float*)d_in[33];  const float* bt=(const float*)d_in[34];
  const float* lhg=(const float*)d_in[35]; const float* lhb=(const float*)d_in[36];
  const float* Wdec=(const float*)d_in[37]; const float* bdec=(const float*)d_in[38];
  float* out = (float*)d_out;

  // workspace layout (u16 units)
  u16* ws     = (u16*)d_ws;
  u16* WT     = ws;                          // 24,030,720 u16 (reused per layer / head)
  u16* h_bf   = WT + 24030720;               // 1,572,864 u16
  float* h_f  = (float*)(h_bf + 1572864);    // 1,572,864 f32
  float* h2_f = h_f + 1572864;               // 1,572,864 f32
  u16* qkv    = (u16*)(h2_f + 1572864);      // 4,718,592 u16
  u16* ctx    = qkv + 4718592;               // 1,572,864 u16
  u16* VT     = ctx + 1572864;               // 1,572,864 u16
  u16* enc_bf = VT + 1572864;                // 1,572,864 u16
  u16* Smat   = enc_bf + 1572864;            // 12,582,912 u16
  u16* mid    = Smat;                        // 6,291,456 u16 (FFN only)
  if (ws_size < (size_t)53915136 * 2) return;

  const int DD = 589824, DF = 2359296;
  u16* qkvT = WT;                 // 2304x768
  u16* woT  = WT + 1769472;       // 768x768
  u16* cqT  = WT + 2359296;       // 768x768
  u16* ckvT = WT + 2949120;       // 1536x768
  u16* cwoT = WT + 4128768;       // 768x768
  u16* wiT  = WT + 4718592;       // 3072x768
  u16* wfT  = WT + 7077888;       // 768x3072

  embed_kernel<<<2048, 256, 0, stream>>>(ids, wemb, pemb, temb, eg, eb, h_f, h_bf);
  cvt_kernel<<<1536, 256, 0, stream>>>(enc, enc_bf, 1572864);

  for (int l = 0; l < 6; l++) {
    TransArgs ta; int tile = 0; int idx = 0;
    auto add = [&](const float* s, u16* d, int K, int N) {
      ta.e[idx].src=s; ta.e[idx].dst=d; ta.e[idx].K=K; ta.e[idx].N=N; ta.e[idx].tile0=tile;
      tile += (K/64)*((N+63)/64); idx++;
    };
    add(Wq +(i64)l*DD, qkvT,        768, 768);
    add(Wk +(i64)l*DD, qkvT+DD,     768, 768);
    add(Wv +(i64)l*DD, qkvT+2*DD,   768, 768);
    add(Wo +(i64)l*DD, woT,         768, 768);
    add(cWq+(i64)l*DD, cqT,         768, 768);
    add(cWk+(i64)l*DD, ckvT,        768, 768);
    add(cWv+(i64)l*DD, ckvT+DD,     768, 768);
    add(cWo+(i64)l*DD, cwoT,        768, 768);
    add(Wi +(i64)l*DF, wiT,         768, 3072);
    add(Wf +(i64)l*DF, wfT,         3072, 768);
    ta.n = idx;
    transpose_multi<<<tile, 256, 0, stream>>>(ta);

    // ---- self attention ----
    g3_128(h_bf, 768, qkvT, 768, qkv, 2304, 2048, 2304, 768,
           bq+l*768, bk+l*768, bv+l*768, 768, 0, 0, stream);
    vtrans_kernel<<<dim3(8,1,48), 256, 0, stream>>>(qkv, VT);
    flash_attn<<<dim3(32,48), 64, 0, stream>>>(qkv, VT, ctx, 1);
    g3_64(ctx, 768, woT, 768, h2_f, 768, 2048, 768, 768,
          bo+l*768, nullptr, nullptr, 768, 0, 1, stream);
    resln_kernel<<<2048, 256, 0, stream>>>(h_f, h2_f, l1g+l*768, l1b+l*768, h_f, h_bf);

    // ---- cross attention ----
    g3_64(h_bf, 768, cqT, 768, qkv, 2304, 2048, 768, 768,
          cbq+l*768, nullptr, nullptr, 768, 0, 0, stream);
    g3_64(enc_bf, 768, ckvT, 768, qkv+768, 2304, 2048, 1536, 768,
          cbk+l*768, cbv+l*768, nullptr, 768, 0, 0, stream);
    vtrans_kernel<<<dim3(8,1,48), 256, 0, stream>>>(qkv, VT);
    flash_attn<<<dim3(32,48), 64, 0, stream>>>(qkv, VT, ctx, 0);
    g3_64(ctx, 768, cwoT, 768, h2_f, 768, 2048, 768, 768,
          cbo+l*768, nullptr, nullptr, 768, 0, 1, stream);
    resln_kernel<<<2048, 256, 0, stream>>>(h_f, h2_f, l2g+l*768, l2b+l*768, h_f, h_bf);

    // ---- FFN ----
    g3_128(h_bf, 768, wiT, 768, mid, 3072, 2048, 3072, 768,
           bi+l*3072, nullptr, nullptr, 3072, 1, 0, stream);
    g3_64(mid, 3072, wfT, 3072, h2_f, 768, 2048, 768, 3072,
          bff+l*768, nullptr, nullptr, 768, 0, 1, stream);
    resln_kernel<<<2048, 256, 0, stream>>>(h_f, h2_f, l3g+l*768, l3b+l*768, h_f, h_bf);
  }

  // ---- MLM head ----
  u16* wtT   = WT;            // 768x768
  u16* wdecT = WT + 589824;   // 30522x768
  {
    TransArgs ta; int tile = 0; int idx = 0;
    auto add = [&](const float* s, u16* d, int K, int N) {
      ta.e[idx].src=s; ta.e[idx].dst=d; ta.e[idx].K=K; ta.e[idx].N=N; ta.e[idx].tile0=tile;
      tile += (K/64)*((N+63)/64); idx++;
    };
    add(Wt,   wtT,   768, 768);
    add(Wdec, wdecT, 768, 30522);
    ta.n = idx;
    transpose_multi<<<tile, 256, 0, stream>>>(ta);
  }
  g3_64(h_bf, 768, wtT, 768, h2_f, 768, 2048, 768, 768, bt, nullptr, nullptr, 768, 1, 1, stream);
  resln_kernel<<<2048, 256, 0, stream>>>(nullptr, h2_f, lhg, lhb, h_f, h_bf);
  g3_128(h_bf, 768, wdecT, 768, out, 30522, 2048, 30522, 768,
         bdec, nullptr, nullptr, 30522, 0, 1, stream);
}

// Round 6
// 2170.650 us; speedup vs baseline: 1.4024x; 1.1548x over previous
//
#include <hip/hip_runtime.h>
#include <math.h>

typedef unsigned short u16;
typedef unsigned int   u32;
typedef long long      i64;
typedef __attribute__((ext_vector_type(8))) __bf16 bf16x8;
typedef __attribute__((ext_vector_type(4))) float  f32x4;
typedef __attribute__((ext_vector_type(8))) u16    u16x8;
typedef __attribute__((ext_vector_type(4))) u16    u16x4;

#define LN_EPS 1e-12f

__device__ __forceinline__ float b2f(u16 u){ union {u32 i; float f;} v; v.i = ((u32)u)<<16; return v.f; }
__device__ __forceinline__ u16 f2b(float f){ union {float f; u32 i;} v; v.f = f; u32 r = v.i + 0x7FFFu + ((v.i>>16)&1u); return (u16)(r>>16); }

__device__ __forceinline__ void gl2lds16(const u16* g, u16* l) {
  __builtin_amdgcn_global_load_lds((const __attribute__((address_space(1))) void*)g,
                                   (__attribute__((address_space(3))) void*)l, 16, 0, 0);
}

template<int N> __device__ __forceinline__ void vm_wait() {
  asm volatile("s_waitcnt vmcnt(%0)" :: "i"(N) : "memory");
}
__device__ __forceinline__ void lgkm0() {
  asm volatile("s_waitcnt lgkmcnt(0)" ::: "memory");
}

// ---------------------------------------------------------------- GEMM (B^T), 3-buf 2-deep
// C[m][n] = sum_k A[m][k] * Bt[n][k] (+f32 bias, +gelu). A/Bt bf16; C bf16 or f32.
// Pipeline (T4 counted-vmcnt): per K-step stage(t+2) -> vmcnt(2L) -> s_barrier
// -> ds_read(cur) -> lgkmcnt(0) -> s_barrier -> MFMA. vmcnt never drains to 0
// mid-loop. LDS swizzle: 16B slot s' = s ^ ((row>>1)&3) on BOTH gload source and
// ds_read (verified conflict-free: SQ_LDS_BANK_CONFLICT = 0 since R4).
// A2/n_split: column-gated second A matrix (fused cross-attn Q|KV projection —
// output cols < n_split read A, cols >= n_split read A2).
struct GemmArgs {
  const u16* A; const u16* A2; const u16* Bt; void* C;
  const float* bias0; const float* bias1; const float* bias2;
  int lda, ldb, ldc, M, N, K, bias_seg, act, cf32, n_split;
};

template<int BM, int BN, int WM, int WN>
__global__ __launch_bounds__(WM*WN*64)
void gemm_bt3(GemmArgs g) {
  constexpr int NTHR = WM*WN*64;
  constexpr int MI = BM/(WM*16);
  constexpr int NJ = BN/(WN*16);
  constexpr int RA = (BM*4)/NTHR;   // staging rounds for A (NTHR/4 rows per round)
  constexpr int RB = (BN*4)/NTHR;
  constexpr int L  = RA+RB;         // vmem instrs per wave per stage batch
  __shared__ u16 As[3][BM*32];
  __shared__ u16 Bs[3][BN*32];
  const int tid  = threadIdx.x;
  const int wave = tid >> 6, lane = tid & 63;
  const int wm = wave / WN, wn = wave % WN;
  const int lrow = lane & 15, quad = lane >> 4;

  // XCD-chunked bijective swizzle (m204) for large grids.
  int bx, by;
  {
    const int gx = gridDim.x;
    const int nwg = gx * gridDim.y;
    const int wg = blockIdx.y * gx + blockIdx.x;
    if (nwg >= 512) {
      const int q = nwg >> 3, r = nwg & 7;
      const int xcd = wg & 7, loc = wg >> 3;
      const int nid = (xcd < r ? xcd * (q + 1) : r * (q + 1) + (xcd - r) * q) + loc;
      bx = nid % gx; by = nid / gx;
    } else { bx = blockIdx.x; by = blockIdx.y; }
  }

  const int n0 = by * BN;
  const u16* Asel = (g.A2 && n0 >= g.n_split) ? g.A2 : g.A;
  const u16* Ab = Asel + (i64)bx*BM*g.lda;
  const u16* Bt = g.Bt;

  const int srow = tid >> 2;   // staging: row within round
  const int sps  = tid & 3;    // physical 16B slot within 64B row

  f32x4 acc[MI][NJ];
  #pragma unroll
  for (int i=0;i<MI;i++)
    #pragma unroll
    for (int j=0;j<NJ;j++) acc[i][j] = (f32x4){0.f,0.f,0.f,0.f};

  auto stage = [&](int buf, int k0) {
    #pragma unroll
    for (int la=0; la<RA; ++la) {
      int row = la*(NTHR>>2) + srow;
      int ls = sps ^ ((row>>1)&3);                       // inverse swizzle on source
      const u16* src = Ab + (i64)row*g.lda + k0 + (ls<<3);
      gl2lds16(src, &As[buf][(la*NTHR + (wave<<6))<<3]); // wave-uniform linear dest
    }
    #pragma unroll
    for (int la=0; la<RB; ++la) {
      int row = la*(NTHR>>2) + srow;
      int nrow = n0 + row; if (nrow >= g.N) nrow = g.N-1;  // clamp (stores guarded)
      int ls = sps ^ ((row>>1)&3);
      const u16* src = Bt + (i64)nrow*g.ldb + k0 + (ls<<3);
      gl2lds16(src, &Bs[buf][(la*NTHR + (wave<<6))<<3]);
    }
  };

  const int NT = g.K >> 5;
  stage(0, 0);
  if (NT > 1) stage(1, 32);
  for (int t = 0; t < NT; ++t) {
    const int cur = t % 3;
    if (t+2 < NT) { stage((t+2)%3, (t+2)<<5); vm_wait<2*L>(); }
    else if (t+1 < NT) { vm_wait<L>(); }
    else { vm_wait<0>(); }
    __builtin_amdgcn_s_barrier();           // everyone's batch-t data in LDS
    __builtin_amdgcn_sched_barrier(0);
    const int xr = (lrow>>1)&3;
    bf16x8 a[MI], b[NJ];
    #pragma unroll
    for (int i=0;i<MI;i++) {
      int r = wm*(MI*16) + i*16 + lrow;
      a[i] = *(const bf16x8*)&As[cur][r*32 + ((quad^xr)<<3)];
    }
    #pragma unroll
    for (int j=0;j<NJ;j++) {
      int r = wn*(NJ*16) + j*16 + lrow;
      b[j] = *(const bf16x8*)&Bs[cur][r*32 + ((quad^xr)<<3)];
    }
    lgkm0();                                // my reads complete (LDS-only wait)
    __builtin_amdgcn_s_barrier();           // all reads done -> buffer may be restaged
    __builtin_amdgcn_sched_barrier(0);
    #pragma unroll
    for (int i=0;i<MI;i++)
      #pragma unroll
      for (int j=0;j<NJ;j++)
        acc[i][j] = __builtin_amdgcn_mfma_f32_16x16x32_bf16(a[i], b[j], acc[i][j], 0,0,0);
  }

  const i64 rowbase = (i64)bx*BM + wm*(MI*16);
  u16*   Cb = (u16*)g.C;
  float* Cf = (float*)g.C;
  #pragma unroll
  for (int i=0;i<MI;i++) {
    #pragma unroll
    for (int j=0;j<NJ;j++) {
      int col = n0 + wn*(NJ*16) + (j<<4) + lrow;
      if (col < g.N) {
        float bias = 0.f;
        if (g.bias0) {
          int seg = col / g.bias_seg;
          const float* bp = (seg==0) ? g.bias0 : ((seg==1) ? g.bias1 : g.bias2);
          bias = bp[col - seg*g.bias_seg];
        }
        #pragma unroll
        for (int r=0;r<4;r++) {
          i64 row = rowbase + (i<<4) + (quad<<2) + r;
          float v = acc[i][j][r] + bias;
          if (g.act == 1) v = 0.5f*v*(1.0f + erff(v*0.70710678118654752f));
          if (g.cf32) Cf[row*(i64)g.ldc + col] = v;
          else        Cb[row*(i64)g.ldc + col] = f2b(v);
        }
      }
    }
  }
}

// ---------------------------------------------------------------- fused flash attention
// One wave (64 thr) per (16 q-rows, b, h). Grid (32, 48). No LDS, no barriers.
__global__ __launch_bounds__(64) void flash_attn(const u16* __restrict__ qkv,
                                                 const u16* __restrict__ VT,
                                                 u16* __restrict__ ctx, int causal) {
  const int lane = threadIdx.x & 63;
  const int qi = lane & 15, g = lane >> 4;
  const int q0 = blockIdx.x << 4;            // 16 q-rows per wave
  const int bh = blockIdx.y;
  const int b = bh / 12, h = bh % 12;
  const int q = q0 + qi;

  const u16* Qp = qkv + (i64)(b*512 + q)*2304 + h*64 + (g<<3);
  bf16x8 qf0 = *(const bf16x8*)Qp;
  bf16x8 qf1 = *(const bf16x8*)(Qp + 32);

  const u16* Kp = qkv + ((i64)(b*512 + qi))*2304 + 768 + h*64 + (g<<3);
  const u16* Vp = VT + (i64)bh*32768 + (i64)qi*512 + (g<<3);

  f32x4 o[4];
  #pragma unroll
  for (int s=0;s<4;s++) o[s] = (f32x4){0.f,0.f,0.f,0.f};
  float m = -1e30f, lsum = 0.f;

  const int sA = qi + ((g & 1) << 5);
  const int sB = sA + 16;
  const int tsel = g >> 1;

  const int nt = causal ? (q0 >> 6) + 1 : 8;
  for (int kt = 0; kt < nt; ++kt) {
    const int kv0 = kt << 6;

    bf16x8 kf[4][2];
    #pragma unroll
    for (int t=0;t<4;t++)
      #pragma unroll
      for (int w=0;w<2;w++)
        kf[t][w] = *(const bf16x8*)(Kp + (i64)(kv0 + (t<<4))*2304 + (w<<5));
    bf16x8 vf[4][2];
    #pragma unroll
    for (int s=0;s<4;s++)
      #pragma unroll
      for (int w=0;w<2;w++)
        vf[s][w] = *(const bf16x8*)(Vp + (s<<13) + kv0 + (w<<5));

    f32x4 sc[4];
    #pragma unroll
    for (int t=0;t<4;t++) {
      sc[t] = (f32x4){0.f,0.f,0.f,0.f};
      sc[t] = __builtin_amdgcn_mfma_f32_16x16x32_bf16(kf[t][0], qf0, sc[t], 0,0,0);
      sc[t] = __builtin_amdgcn_mfma_f32_16x16x32_bf16(kf[t][1], qf1, sc[t], 0,0,0);
    }

    float x[4][4];
    #pragma unroll
    for (int t=0;t<4;t++)
      #pragma unroll
      for (int r=0;r<4;r++) {
        float v = sc[t][r] * 0.125f;
        int key = kv0 + (t<<4) + (g<<2) + r;
        if (causal && key > q) v = -1e30f;
        x[t][r] = v;
      }

    float mt = x[0][0];
    #pragma unroll
    for (int t=0;t<4;t++)
      #pragma unroll
      for (int r=0;r<4;r++) mt = fmaxf(mt, x[t][r]);
    mt = fmaxf(mt, __shfl_xor(mt, 16));
    mt = fmaxf(mt, __shfl_xor(mt, 32));
    float mn = fmaxf(m, mt);
    float c = __expf(m - mn);
    m = mn;

    float p[4][4];
    float ps = 0.f;
    #pragma unroll
    for (int t=0;t<4;t++)
      #pragma unroll
      for (int r=0;r<4;r++) { float e = __expf(x[t][r] - mn); p[t][r] = e; ps += e; }
    ps += __shfl_xor(ps, 16);
    ps += __shfl_xor(ps, 32);
    lsum = lsum * c + ps;
    #pragma unroll
    for (int s=0;s<4;s++) o[s] *= c;

    u32 pkLo[4], pkHi[4];
    #pragma unroll
    for (int t=0;t<4;t++) {
      pkLo[t] = (u32)f2b(p[t][0]) | ((u32)f2b(p[t][1]) << 16);
      pkHi[t] = (u32)f2b(p[t][2]) | ((u32)f2b(p[t][3]) << 16);
    }

    #pragma unroll
    for (int w=0;w<2;w++) {
      u32 w0=0, w1=0, w2=0, w3=0;
      #pragma unroll
      for (int tl=0; tl<2; ++tl) {
        const int t = 2*w + tl;
        u32 aLo = (u32)__shfl((int)pkLo[t], sA);
        u32 aHi = (u32)__shfl((int)pkHi[t], sA);
        u32 bLo = (u32)__shfl((int)pkLo[t], sB);
        u32 bHi = (u32)__shfl((int)pkHi[t], sB);
        if (tsel == tl) { w0=aLo; w1=aHi; w2=bLo; w3=bHi; }
      }
      union { bf16x8 v; u32 u[4]; } pf;
      pf.u[0]=w0; pf.u[1]=w1; pf.u[2]=w2; pf.u[3]=w3;
      #pragma unroll
      for (int s=0;s<4;s++)
        o[s] = __builtin_amdgcn_mfma_f32_16x16x32_bf16(vf[s][w], pf.v, o[s], 0,0,0);
    }
  }

  float inv = 1.0f / lsum;
  u16* orow = ctx + (i64)(b*512 + q)*768 + h*64 + (g<<2);
  #pragma unroll
  for (int s=0;s<4;s++) {
    u16x4 ov;
    #pragma unroll
    for (int r=0;r<4;r++) ov[r] = f2b(o[s][r] * inv);
    *(u16x4*)(orow + (s<<4)) = ov;
  }
}

// ---------------------------------------------------------------- LN helpers
__device__ __forceinline__ float block_reduce_sum_256(float v, float* red) {
  #pragma unroll
  for (int off=32; off; off>>=1) v += __shfl_xor(v, off);
  int wave = threadIdx.x >> 6;
  __syncthreads();
  if ((threadIdx.x & 63) == 0) red[wave] = v;
  __syncthreads();
  return red[0]+red[1]+red[2]+red[3];
}

__global__ __launch_bounds__(256) void resln_kernel(const float* base, const float* delta,
                                                    const float* gam, const float* bet,
                                                    float* out_f, u16* out_b) {
  __shared__ float red[4];
  i64 off = (i64)blockIdx.x * 768;
  int tid = threadIdx.x;
  float x[3];
  #pragma unroll
  for (int j=0;j<3;j++) {
    int i = tid + j*256;
    float v = delta[off+i];
    if (base) v += base[off+i];
    x[j] = v;
  }
  float s = block_reduce_sum_256(x[0]+x[1]+x[2], red);
  float mean = s * (1.0f/768.0f);
  float q = 0.f;
  #pragma unroll
  for (int j=0;j<3;j++) { float d = x[j]-mean; q += d*d; }
  q = block_reduce_sum_256(q, red);
  float r = rsqrtf(q*(1.0f/768.0f) + LN_EPS);
  #pragma unroll
  for (int j=0;j<3;j++) {
    int i = tid + j*256;
    float y = (x[j]-mean)*r*gam[i] + bet[i];
    out_f[off+i] = y;
    out_b[off+i] = f2b(y);
  }
}

__global__ __launch_bounds__(256) void embed_kernel(const int* ids, const float* wemb,
    const float* pemb, const float* temb, const float* gam, const float* bet,
    float* out_f, u16* out_b) {
  __shared__ float red[4];
  int row = blockIdx.x;
  int s = row & 511;
  i64 wrow = (i64)ids[row] * 768;
  i64 off = (i64)row * 768;
  int tid = threadIdx.x;
  float x[3];
  #pragma unroll
  for (int j=0;j<3;j++) {
    int i = tid + j*256;
    x[j] = wemb[wrow+i] + pemb[(i64)s*768+i] + temb[i];
  }
  float sm = block_reduce_sum_256(x[0]+x[1]+x[2], red);
  float mean = sm * (1.0f/768.0f);
  float q = 0.f;
  #pragma unroll
  for (int j=0;j<3;j++) { float d = x[j]-mean; q += d*d; }
  q = block_reduce_sum_256(q, red);
  float r = rsqrtf(q*(1.0f/768.0f) + LN_EPS);
  #pragma unroll
  for (int j=0;j<3;j++) {
    int i = tid + j*256;
    float y = (x[j]-mean)*r*gam[i] + bet[i];
    out_f[off+i] = y;
    out_b[off+i] = f2b(y);
  }
}

__global__ __launch_bounds__(256) void cvt_kernel(const float* src, u16* dst, int n) {
  int i = (blockIdx.x*256 + threadIdx.x) * 4;
  if (i + 3 < n) {
    float4 v = *(const float4*)&src[i];
    dst[i+0]=f2b(v.x); dst[i+1]=f2b(v.y); dst[i+2]=f2b(v.z); dst[i+3]=f2b(v.w);
  }
}

// ---------------------------------------------------------------- transposes
struct TransEntry { const float* src; u16* dst; int K, N, tile0; };
struct TransArgs  { TransEntry e[12]; int n; };

__global__ __launch_bounds__(256) void transpose_multi(TransArgs ta) {
  __shared__ u16 tile[64][72];
  int t = blockIdx.x;
  int ei = 0;
  for (int i=1;i<ta.n;i++) if (t >= ta.e[i].tile0) ei = i;
  TransEntry E = ta.e[ei];
  int lt = t - E.tile0;
  int ntn = (E.N + 63) >> 6;
  int tk = lt / ntn, tn = lt - tk*ntn;
  int tid = threadIdx.x;
  int kk = tid >> 2, c = (tid & 3) << 4;
  i64 gk = (i64)(tk*64 + kk);
  int gn0 = tn*64 + c;
  const float* srow = E.src + gk * E.N;
  if (gn0 + 16 <= E.N) {
    #pragma unroll
    for (int j=0;j<16;j++) tile[kk][c+j] = f2b(srow[gn0+j]);
  } else {
    for (int j=0;j<16;j++) tile[kk][c+j] = (gn0+j < E.N) ? f2b(srow[gn0+j]) : (u16)0;
  }
  __syncthreads();
  int nn = tid >> 2, kc = (tid & 3) << 4;
  int gn = tn*64 + nn;
  if (gn < E.N) {
    u16x8 v0, v1;
    #pragma unroll
    for (int j=0;j<8;j++) { v0[j] = tile[kc+j][nn]; v1[j] = tile[kc+8+j][nn]; }
    u16* drow = E.dst + (i64)gn*E.K + tk*64 + kc;
    *(u16x8*)&drow[0] = v0;
    *(u16x8*)&drow[8] = v1;
  }
}

// VT[bh][d][key] = qkv[b*512+key][1536 + h*64 + d]   (bf16 -> bf16)
__global__ __launch_bounds__(256) void vtrans_kernel(const u16* qkv, u16* VT) {
  __shared__ u16 tile[64][72];
  int bh = blockIdx.z; int b = bh / 12, hh = bh % 12;
  const u16* src = qkv + (i64)b*512*2304 + 1536 + hh*64;
  u16* dst = VT + (i64)bh*64*512;
  int kt = blockIdx.x;
  int tid = threadIdx.x;
  int kk = tid >> 2, c = (tid & 3) << 4;
  const u32* p = (const u32*)&src[(i64)(kt*64+kk)*2304 + c];
  #pragma unroll
  for (int j=0;j<8;j++) *(u32*)&tile[kk][c + 2*j] = p[j];
  __syncthreads();
  int dd = tid >> 2, kc = (tid & 3) << 4;
  u16x8 v0, v1;
  #pragma unroll
  for (int j=0;j<8;j++) { v0[j] = tile[kc+j][dd]; v1[j] = tile[kc+8+j][dd]; }
  u16* drow = dst + (i64)dd*512 + kt*64 + kc;
  *(u16x8*)&drow[0] = v0;
  *(u16x8*)&drow[8] = v1;
}

// ---------------------------------------------------------------- host side
static void gemm_args(GemmArgs& g, const u16* A, const u16* A2, int n_split,
                      int lda, const u16* Bt, int ldb,
                      void* C, int ldc, int M, int N, int K, const float* b0,
                      const float* b1, const float* b2, int bias_seg, int act, int cf32) {
  g.A=A; g.A2=A2; g.Bt=Bt; g.C=C; g.bias0=b0; g.bias1=b1; g.bias2=b2;
  g.lda=lda; g.ldb=ldb; g.ldc=ldc; g.M=M; g.N=N; g.K=K;
  g.bias_seg=bias_seg; g.act=act; g.cf32=cf32; g.n_split=n_split;
}

// vocab / big-N path: 128x128, 4 waves, 64x64 per wave
static void g3_128(const u16* A, int lda, const u16* Bt, int ldb, void* C, int ldc,
                   int M, int N, int K, const float* b0, const float* b1, const float* b2,
                   int bias_seg, int act, int cf32, hipStream_t st) {
  GemmArgs g; gemm_args(g, A, nullptr, 0, lda, Bt, ldb, C, ldc, M, N, K, b0, b1, b2, bias_seg, act, cf32);
  gemm_bt3<128,128,2,2><<<dim3(M/128, (N+127)/128), 256, 0, st>>>(g);
}

// layer path: 64x128, 4 waves, 64x32 per wave -> 2x wave count of the old g3_64.
static void g4(const u16* A, const u16* A2, int n_split, int lda,
               const u16* Bt, int ldb, void* C, int ldc,
               int M, int N, int K, const float* b0, const float* b1, const float* b2,
               int bias_seg, int act, int cf32, hipStream_t st) {
  GemmArgs g; gemm_args(g, A, A2, n_split, lda, Bt, ldb, C, ldc, M, N, K, b0, b1, b2, bias_seg, act, cf32);
  gemm_bt3<64,128,1,4><<<dim3(M/64, (N+127)/128), 256, 0, st>>>(g);
}

extern "C" void kernel_launch(void* const* d_in, const int* in_sizes, int n_in,
                              void* d_out, int out_size, void* d_ws, size_t ws_size,
                              hipStream_t stream) {
  (void)in_sizes; (void)n_in; (void)out_size;
  const int*   ids  = (const int*)d_in[0];
  const float* enc  = (const float*)d_in[1];
  const float* wemb = (const float*)d_in[2];
  const float* pemb = (const float*)d_in[3];
  const float* temb = (const float*)d_in[4];
  const float* eg   = (const float*)d_in[5];
  const float* eb   = (const float*)d_in[6];
  const float* Wq=(const float*)d_in[7];  const float* bq=(const float*)d_in[8];
  const float* Wk=(const float*)d_in[9];  const float* bk=(const float*)d_in[10];
  const float* Wv=(const float*)d_in[11]; const float* bv=(const float*)d_in[12];
  const float* Wo=(const float*)d_in[13]; const float* bo=(const float*)d_in[14];
  const float* l1g=(const float*)d_in[15]; const float* l1b=(const float*)d_in[16];
  const float* cWq=(const float*)d_in[17]; const float* cbq=(const float*)d_in[18];
  const float* cWk=(const float*)d_in[19]; const float* cbk=(const float*)d_in[20];
  const float* cWv=(const float*)d_in[21]; const float* cbv=(const float*)d_in[22];
  const float* cWo=(const float*)d_in[23]; const float* cbo=(const float*)d_in[24];
  const float* l2g=(const float*)d_in[25]; const float* l2b=(const float*)d_in[26];
  const float* Wi=(const float*)d_in[27];  const float* bi=(const float*)d_in[28];
  const float* Wf=(const float*)d_in[29];  const float* bff=(const float*)d_in[30];
  const float* l3g=(const float*)d_in[31]; const float* l3b=(const float*)d_in[32];
  const float* Wt=(const float*)d_in[33];  const float* bt=(const float*)d_in[34];
  const float* lhg=(const float*)d_in[35]; const float* lhb=(const float*)d_in[36];
  const float* Wdec=(const float*)d_in[37]; const float* bdec=(const float*)d_in[38];
  float* out = (float*)d_out;

  // workspace layout (u16 units)
  u16* ws     = (u16*)d_ws;
  u16* WT     = ws;                          // 24,030,720 u16 (reused per layer / head)
  u16* h_bf   = WT + 24030720;               // 1,572,864 u16
  float* h_f  = (float*)(h_bf + 1572864);    // 1,572,864 f32
  float* h2_f = h_f + 1572864;               // 1,572,864 f32
  u16* qkv    = (u16*)(h2_f + 1572864);      // 4,718,592 u16
  u16* ctx    = qkv + 4718592;               // 1,572,864 u16
  u16* VT     = ctx + 1572864;               // 1,572,864 u16
  u16* enc_bf = VT + 1572864;                // 1,572,864 u16
  u16* Smat   = enc_bf + 1572864;            // 12,582,912 u16
  u16* mid    = Smat;                        // 6,291,456 u16 (FFN only)
  if (ws_size < (size_t)53915136 * 2) return;

  const int DD = 589824, DF = 2359296;
  u16* qkvT = WT;                 // 2304x768
  u16* woT  = WT + 1769472;       // 768x768
  u16* cqT  = WT + 2359296;       // 768x768   (cqT..ckvT contiguous: 2304x768 merged B)
  u16* ckvT = WT + 2949120;       // 1536x768
  u16* cwoT = WT + 4128768;       // 768x768
  u16* wiT  = WT + 4718592;       // 3072x768
  u16* wfT  = WT + 7077888;       // 768x3072

  embed_kernel<<<2048, 256, 0, stream>>>(ids, wemb, pemb, temb, eg, eb, h_f, h_bf);
  cvt_kernel<<<1536, 256, 0, stream>>>(enc, enc_bf, 1572864);

  for (int l = 0; l < 6; l++) {
    TransArgs ta; int tile = 0; int idx = 0;
    auto add = [&](const float* s, u16* d, int K, int N) {
      ta.e[idx].src=s; ta.e[idx].dst=d; ta.e[idx].K=K; ta.e[idx].N=N; ta.e[idx].tile0=tile;
      tile += (K/64)*((N+63)/64); idx++;
    };
    add(Wq +(i64)l*DD, qkvT,        768, 768);
    add(Wk +(i64)l*DD, qkvT+DD,     768, 768);
    add(Wv +(i64)l*DD, qkvT+2*DD,   768, 768);
    add(Wo +(i64)l*DD, woT,         768, 768);
    add(cWq+(i64)l*DD, cqT,         768, 768);
    add(cWk+(i64)l*DD, ckvT,        768, 768);
    add(cWv+(i64)l*DD, ckvT+DD,     768, 768);
    add(cWo+(i64)l*DD, cwoT,        768, 768);
    add(Wi +(i64)l*DF, wiT,         768, 3072);
    add(Wf +(i64)l*DF, wfT,         3072, 768);
    ta.n = idx;
    transpose_multi<<<tile, 256, 0, stream>>>(ta);

    // ---- self attention ----
    g4(h_bf, nullptr, 0, 768, qkvT, 768, qkv, 2304, 2048, 2304, 768,
       bq+l*768, bk+l*768, bv+l*768, 768, 0, 0, stream);
    vtrans_kernel<<<dim3(8,1,48), 256, 0, stream>>>(qkv, VT);
    flash_attn<<<dim3(32,48), 64, 0, stream>>>(qkv, VT, ctx, 1);
    g4(ctx, nullptr, 0, 768, woT, 768, h2_f, 768, 2048, 768, 768,
       bo+l*768, nullptr, nullptr, 768, 0, 1, stream);
    resln_kernel<<<2048, 256, 0, stream>>>(h_f, h2_f, l1g+l*768, l1b+l*768, h_f, h_bf);

    // ---- cross attention (fused Q|KV projection: cols<768 read h_bf, else enc_bf) ----
    g4(h_bf, enc_bf, 768, 768, cqT, 768, qkv, 2304, 2048, 2304, 768,
       cbq+l*768, cbk+l*768, cbv+l*768, 768, 0, 0, stream);
    vtrans_kernel<<<dim3(8,1,48), 256, 0, stream>>>(qkv, VT);
    flash_attn<<<dim3(32,48), 64, 0, stream>>>(qkv, VT, ctx, 0);
    g4(ctx, nullptr, 0, 768, cwoT, 768, h2_f, 768, 2048, 768, 768,
       cbo+l*768, nullptr, nullptr, 768, 0, 1, stream);
    resln_kernel<<<2048, 256, 0, stream>>>(h_f, h2_f, l2g+l*768, l2b+l*768, h_f, h_bf);

    // ---- FFN ----
    g4(h_bf, nullptr, 0, 768, wiT, 768, mid, 3072, 2048, 3072, 768,
       bi+l*3072, nullptr, nullptr, 3072, 1, 0, stream);
    g4(mid, nullptr, 0, 3072, wfT, 3072, h2_f, 768, 2048, 768, 3072,
       bff+l*768, nullptr, nullptr, 768, 0, 1, stream);
    resln_kernel<<<2048, 256, 0, stream>>>(h_f, h2_f, l3g+l*768, l3b+l*768, h_f, h_bf);
  }

  // ---- MLM head ----
  u16* wtT   = WT;            // 768x768
  u16* wdecT = WT + 589824;   // 30522x768
  {
    TransArgs ta; int tile = 0; int idx = 0;
    auto add = [&](const float* s, u16* d, int K, int N) {
      ta.e[idx].src=s; ta.e[idx].dst=d; ta.e[idx].K=K; ta.e[idx].N=N; ta.e[idx].tile0=tile;
      tile += (K/64)*((N+63)/64); idx++;
    };
    add(Wt,   wtT,   768, 768);
    add(Wdec, wdecT, 768, 30522);
    ta.n = idx;
    transpose_multi<<<tile, 256, 0, stream>>>(ta);
  }
  g4(h_bf, nullptr, 0, 768, wtT, 768, h2_f, 768, 2048, 768, 768,
     bt, nullptr, nullptr, 768, 1, 1, stream);
  resln_kernel<<<2048, 256, 0, stream>>>(nullptr, h2_f, lhg, lhb, h_f, h_bf);
  g3_128(h_bf, 768, wdecT, 768, out, 30522, 2048, 30522, 768,
         bdec, nullptr, nullptr, 30522, 0, 1, stream);
}